// Round 5
// baseline (403.329 us; speedup 1.0000x reference)
//
#include <hip/hip_runtime.h>
#include <stdint.h>

typedef unsigned short u16;
typedef __attribute__((ext_vector_type(8))) __bf16 bf16x8;
typedef __attribute__((ext_vector_type(8))) short short8s;
typedef __attribute__((ext_vector_type(4))) float float4v;

// ---------- sizes ----------
static constexpr int NB = 4, NC = 256, NH = 64, NW = 64, NHW = 4096;
static constexpr int BC = 32;        // kv tile
static constexpr int NKV = 4;        // kv split factor
static constexpr int KVCHUNK = NHW / NKV;   // 1024

// ---------- workspace layout (lifetime-aliased) ----------
static constexpr size_t MB = 1ull << 20;
static constexpr size_t OFF_KBF    = 0;          // bf16 [B][C][N] 8MB (dead after transpose)
static constexpr size_t OFF_LBF    = 8 * MB;     // bf16 [B][C][N] 8MB (dead after transpose)
static constexpr size_t OFF_GT     = 0;          // bf16 [B][N][C] 8MB — overlays KBF (combine writes after KBF dead)
static constexpr size_t OFF_XT     = 16 * MB;    // bf16 [B][N][C] 8MB (dead after gemm_q)
static constexpr size_t OFF_FUSEDT = 16 * MB;    // bf16 [B][N][C] 8MB — overlays XT
static constexpr size_t OFF_QT     = 24 * MB;    // bf16 [B][N][C] 8MB
static constexpr size_t OFF_KT     = 32 * MB;    // bf16 [B][N][C] 8MB
static constexpr size_t OFF_VBF    = 40 * MB;    // bf16 [B][C][N] 8MB
static constexpr size_t OFF_LT     = 48 * MB;    // bf16 [B][N][C] 8MB (localT)
static constexpr size_t OFF_OPART  = 56 * MB;    // bf16 [B][NKV][N][C] 32MB
static constexpr size_t OFF_LPART  = 88 * MB;    // fp32 [B][NKV][N] 256KB
static constexpr size_t OFF_HIDT   = OFF_LPART + 256 * 1024;   // bf16 [B][N][64] 2MB
static constexpr size_t OFF_GAP    = OFF_HIDT + 2 * MB;        // fp32 [B][256]
static constexpr size_t OFF_CW     = OFF_GAP + 8 * 1024;       // fp32 [B][256]
static constexpr size_t OFF_WQB    = OFF_CW + 8 * 1024;        // bf16 256x256
static constexpr size_t OFF_WS1B   = OFF_WQB + 131072;         // bf16 64x256
static constexpr size_t OFF_WS2B   = OFF_WS1B + 32768;         // bf16 256x64
static constexpr size_t OFF_WOB    = OFF_WS2B + 32768;         // bf16 256x256

__device__ __forceinline__ float b2f(u16 h) {
    union { float f; unsigned u; } v; v.u = ((unsigned)h) << 16; return v.f;
}
__device__ __forceinline__ u16 f2b(float f) {
    union { float f; unsigned u; } v; v.f = f;
    unsigned r = v.u + 0x7fffu + ((v.u >> 16) & 1u);
    return (u16)(r >> 16);
}

// async global->LDS, 16B per lane; ldst wave-uniform (HW adds lane*16)
__device__ __forceinline__ void load_lds16(const void* gsrc, void* ldst) {
    __builtin_amdgcn_global_load_lds(
        (__attribute__((address_space(1))) void*)(uintptr_t)gsrc,
        (__attribute__((address_space(3))) void*)ldst,
        16, 0, 0);
}

// ---------- weight fp32->bf16 conversion ----------
__global__ __launch_bounds__(256) void convert_weights(
    const float* __restrict__ Wq, const float* __restrict__ Ws1,
    const float* __restrict__ Ws2, const float* __restrict__ Wo,
    u16* __restrict__ Wqb, u16* __restrict__ Ws1b, u16* __restrict__ Ws2b, u16* __restrict__ Wob)
{
    int id = blockIdx.x * 256 + threadIdx.x;
    if (id < 65536)        Wqb[id] = f2b(Wq[id]);
    else if (id < 81920)   Ws1b[id - 65536] = f2b(Ws1[id - 65536]);
    else if (id < 98304)   Ws2b[id - 81920] = f2b(Ws2[id - 81920]);
    else                   Wob[id - 98304] = f2b(Wo[id - 98304]);
}

// ---------- 9-tap dw conv helper (zero-pad SAME); returns 0 for invalid y ----------
__device__ __forceinline__ float dw9(const float* __restrict__ xb, const float* wgt,
                                     float bias, int y, int xx0)
{
    if ((unsigned)y > 63u) return 0.f;
    float a = bias;
#pragma unroll
    for (int dy = 0; dy < 3; dy++) {
        int yy = y + dy - 1;
        if (yy < 0 || yy > 63) continue;
#pragma unroll
        for (int dx = 0; dx < 3; dx++) {
            int xx = xx0 + dx - 1;
            if (xx < 0 || xx > 63) continue;
            a += wgt[dy * 3 + dx] * xb[yy * 64 + xx];
        }
    }
    return a;
}

// ---------- fused depthwise: k, v, local in one pass (v-row ring in LDS) ----------
// grid (8 y-tiles, 64 c-groups, B); 256 thr = 64 x * 4 ch; 8 output rows per block
__global__ __launch_bounds__(256) void dw_fused(
    const float* __restrict__ x,
    const float* __restrict__ Wk, const float* __restrict__ bk,
    const float* __restrict__ Wv, const float* __restrict__ bv,
    const float* __restrict__ Wl, const float* __restrict__ bl,
    u16* __restrict__ k_bf, u16* __restrict__ vN, u16* __restrict__ local_bf)
{
    __shared__ float vt[4][3][64];
    int t = threadIdx.x;
    int xx0 = t & 63, cl = t >> 6;
    int y0 = blockIdx.x * 8;
    int c  = blockIdx.y * 4 + cl;
    int b  = blockIdx.z;
    const float* xb = x + ((size_t)b * NC + c) * NHW;
    float wk[9], wv[9], wl[9];
#pragma unroll
    for (int i = 0; i < 9; i++) { wk[i] = Wk[c*9+i]; wv[i] = Wv[c*9+i]; wl[i] = Wl[c*9+i]; }
    float bkc = bk[c], bvc = bv[c], blc = bl[c];

    // prologue: v rows y0-1, y0
    vt[cl][(y0 + 2) % 3][xx0] = dw9(xb, wv, bvc, y0 - 1, xx0);
    vt[cl][y0 % 3][xx0]       = dw9(xb, wv, bvc, y0, xx0);

    size_t base = ((size_t)b * NC + c) * NHW;
#pragma unroll 1
    for (int y = y0; y < y0 + 8; y++) {
        vt[cl][(y + 1) % 3][xx0] = dw9(xb, wv, bvc, y + 1, xx0);
        __syncthreads();
        float ak = dw9(xb, wk, bkc, y, xx0);
        float al = blc;
#pragma unroll
        for (int dy = 0; dy < 3; dy++) {
            int yy = y + dy - 1;              // vt holds 0 for invalid rows
            const float* vrow = vt[cl][(yy + 3) % 3];
#pragma unroll
            for (int dx = 0; dx < 3; dx++) {
                int xx = xx0 + dx - 1;
                if (xx < 0 || xx > 63) continue;
                al += wl[dy * 3 + dx] * vrow[xx];
            }
        }
        size_t o = base + y * 64 + xx0;
        k_bf[o]     = f2b(ak);
        vN[o]       = f2b(vt[cl][y % 3][xx0]);
        local_bf[o] = f2b(al);
        __syncthreads();   // before next iter overwrites slot (y+2)%3
    }
}

// ---------- bf16 transpose [C][N] -> [N][C] for k and local ----------
__global__ __launch_bounds__(256) void transpose_bf(
    const u16* __restrict__ k_bf, const u16* __restrict__ local_bf,
    u16* __restrict__ kT, u16* __restrict__ localT)
{
    __shared__ u16 tile[64][72];
    int n0 = blockIdx.x * 64, c0 = blockIdx.y * 64;
    int zb = blockIdx.z, b = zb >> 1;
    const u16* src = (zb & 1) ? local_bf : k_bf;
    u16* dst = (zb & 1) ? localT : kT;
    src += (size_t)b * NC * NHW;
    dst += (size_t)b * NHW * NC;
    int t = threadIdx.x;
    int c = t >> 2, nb = (t & 3) * 16;
    *(short8s*)&tile[c][nb]     = *(const short8s*)(src + (size_t)(c0 + c) * NHW + n0 + nb);
    *(short8s*)&tile[c][nb + 8] = *(const short8s*)(src + (size_t)(c0 + c) * NHW + n0 + nb + 8);
    __syncthreads();
    int cl = t & 63, ng = t >> 6;
#pragma unroll
    for (int j = 0; j < 16; j++) {
        int n = ng * 16 + j;
        dst[(size_t)(n0 + n) * NC + c0 + cl] = tile[cl][n];
    }
}

// ---------- fp32 [C][N] -> bf16 [N][C] transpose-convert for x ----------
__global__ __launch_bounds__(256) void transpose_f2b(
    const float* __restrict__ x, u16* __restrict__ xT)
{
    __shared__ u16 tile[64][72];
    int n0 = blockIdx.x * 64, c0 = blockIdx.y * 64, b = blockIdx.z;
    const float* src = x + (size_t)b * NC * NHW;
    u16* dst = xT + (size_t)b * NHW * NC;
    int t = threadIdx.x;
    int c = t >> 2, nb = (t & 3) * 16;
#pragma unroll
    for (int q = 0; q < 4; q++) {
        float4 v = *(const float4*)(src + (size_t)(c0 + c) * NHW + n0 + nb + q * 4);
        tile[c][nb + q * 4 + 0] = f2b(v.x);
        tile[c][nb + q * 4 + 1] = f2b(v.y);
        tile[c][nb + q * 4 + 2] = f2b(v.z);
        tile[c][nb + q * 4 + 3] = f2b(v.w);
    }
    __syncthreads();
    int cl = t & 63, ng = t >> 6;
#pragma unroll
    for (int j = 0; j < 16; j++) {
        int n = ng * 16 + j;
        dst[(size_t)(n0 + n) * NC + c0 + cl] = tile[cl][n];
    }
}

// ---------- MFMA GEMM: qT[n][cout] = xT[n][:] . Wq[cout][:] + bq ----------
__global__ __launch_bounds__(256) void gemm_q_mfma(
    const u16* __restrict__ xT, const u16* __restrict__ Wqb, const float* __restrict__ bq,
    u16* __restrict__ qT)
{
    const int t = threadIdx.x, w = t >> 6, lane = t & 63;
    const int lm = lane & 15, quad = lane >> 4;
    const int b = blockIdx.y;
    const int s_base = blockIdx.x * 32 + (w & 1) * 16;
    const int ch = (w >> 1) * 128;
    const u16* xTb = xT + (size_t)b * NHW * NC;
    u16* qTb = qT + (size_t)b * NHW * NC;

    bf16x8 aq[8];
#pragma unroll
    for (int kt = 0; kt < 8; kt++)
        aq[kt] = *(const bf16x8*)(xTb + (size_t)(s_base + lm) * NC + kt * 32 + quad * 8);

    float4v acc[8];
#pragma unroll
    for (int j = 0; j < 8; j++) acc[j] = (float4v){0.f, 0.f, 0.f, 0.f};

#pragma unroll
    for (int kt = 0; kt < 8; kt++) {
#pragma unroll
        for (int j = 0; j < 8; j++) {
            bf16x8 bw = *(const bf16x8*)(Wqb + (size_t)(ch + j * 16 + lm) * 256 + kt * 32 + quad * 8);
            acc[j] = __builtin_amdgcn_mfma_f32_16x16x32_bf16(aq[kt], bw, acc[j], 0, 0, 0);
        }
    }
#pragma unroll
    for (int j = 0; j < 8; j++) {
        int cout = ch + j * 16 + lm;
        float bb = bq[cout];
#pragma unroll
        for (int r = 0; r < 4; r++) {
            int s = s_base + quad * 4 + r;
            qTb[(size_t)s * NC + cout] = f2b(acc[j][r] + bb);
        }
    }
}

// ---------- MFMA GEMM: hidT[n][h] = relu(localT[n][:] . Ws1[h][:] + bs1) ----------
__global__ __launch_bounds__(256) void gemm_hid_mfma(
    const u16* __restrict__ localT, const u16* __restrict__ Ws1b, const float* __restrict__ bs1,
    u16* __restrict__ hidT)
{
    const int t = threadIdx.x, w = t >> 6, lane = t & 63;
    const int lm = lane & 15, quad = lane >> 4;
    const int b = blockIdx.y;
    const int s_base = blockIdx.x * 32 + (w & 1) * 16;
    const int ch = (w >> 1) * 32;
    const u16* lTb = localT + (size_t)b * NHW * NC;
    u16* hTb = hidT + (size_t)b * NHW * 64;

    bf16x8 aq[8];
#pragma unroll
    for (int kt = 0; kt < 8; kt++)
        aq[kt] = *(const bf16x8*)(lTb + (size_t)(s_base + lm) * NC + kt * 32 + quad * 8);

    float4v acc[2];
#pragma unroll
    for (int j = 0; j < 2; j++) acc[j] = (float4v){0.f, 0.f, 0.f, 0.f};

#pragma unroll
    for (int kt = 0; kt < 8; kt++) {
#pragma unroll
        for (int j = 0; j < 2; j++) {
            bf16x8 bw = *(const bf16x8*)(Ws1b + (size_t)(ch + j * 16 + lm) * 256 + kt * 32 + quad * 8);
            acc[j] = __builtin_amdgcn_mfma_f32_16x16x32_bf16(aq[kt], bw, acc[j], 0, 0, 0);
        }
    }
#pragma unroll
    for (int j = 0; j < 2; j++) {
        int h = ch + j * 16 + lm;
        float bb = bs1[h];
#pragma unroll
        for (int r = 0; r < 4; r++) {
            int s = s_base + quad * 4 + r;
            hTb[(size_t)s * 64 + h] = f2b(fmaxf(acc[j][r] + bb, 0.0f));
        }
    }
}

// ---------- MFMA GEMM + fuse: fusedT = gT*cw + localT*sigmoid(hidT.Ws2^T + bs2) ----------
__global__ __launch_bounds__(256) void gemm_swfused_mfma(
    const u16* __restrict__ hidT, const u16* __restrict__ Ws2b, const float* __restrict__ bs2,
    const u16* __restrict__ gT, const u16* __restrict__ localT, const float* __restrict__ cw,
    u16* __restrict__ fusedT)
{
    const int t = threadIdx.x, w = t >> 6, lane = t & 63;
    const int lm = lane & 15, quad = lane >> 4;
    const int b = blockIdx.y;
    const int s_base = blockIdx.x * 32 + (w & 1) * 16;
    const int ch = (w >> 1) * 128;
    const u16* hTb = hidT + (size_t)b * NHW * 64;
    const u16* lTb = localT + (size_t)b * NHW * NC;
    const u16* gTb = gT + (size_t)b * NHW * NC;
    u16* fTb = fusedT + (size_t)b * NHW * NC;

    bf16x8 aq[2];
#pragma unroll
    for (int kt = 0; kt < 2; kt++)
        aq[kt] = *(const bf16x8*)(hTb + (size_t)(s_base + lm) * 64 + kt * 32 + quad * 8);

    float4v acc[8];
#pragma unroll
    for (int j = 0; j < 8; j++) acc[j] = (float4v){0.f, 0.f, 0.f, 0.f};

#pragma unroll
    for (int kt = 0; kt < 2; kt++) {
#pragma unroll
        for (int j = 0; j < 8; j++) {
            bf16x8 bw = *(const bf16x8*)(Ws2b + (size_t)(ch + j * 16 + lm) * 64 + kt * 32 + quad * 8);
            acc[j] = __builtin_amdgcn_mfma_f32_16x16x32_bf16(aq[kt], bw, acc[j], 0, 0, 0);
        }
    }
#pragma unroll
    for (int j = 0; j < 8; j++) {
        int c = ch + j * 16 + lm;
        float bb = bs2[c];
        float cwv = cw[b * NC + c];
#pragma unroll
        for (int r = 0; r < 4; r++) {
            int s = s_base + quad * 4 + r;
            float sw = 1.0f / (1.0f + __expf(-(acc[j][r] + bb)));
            float g = b2f(gTb[(size_t)s * NC + c]);
            float lo = b2f(lTb[(size_t)s * NC + c]);
            fTb[(size_t)s * NC + c] = f2b(g * cwv + lo * sw);
        }
    }
}

// ---------- MFMA GEMM: out[o][n] = Wo[o][:] . fusedT[n][:] + bo + x ----------
__global__ __launch_bounds__(256) void gemm_out_mfma(
    const u16* __restrict__ Wob, const u16* __restrict__ fusedT, const float* __restrict__ bo,
    const float* __restrict__ x, float* __restrict__ out)
{
    const int t = threadIdx.x, w = t >> 6, lane = t & 63;
    const int lm = lane & 15, quad = lane >> 4;
    const int b = blockIdx.z;
    const int o_base = blockIdx.x * 32 + (w & 1) * 16;
    const int n_base = blockIdx.y * 256 + (w >> 1) * 128;
    const u16* fTb = fusedT + (size_t)b * NHW * NC;

    bf16x8 aw[8];
#pragma unroll
    for (int kt = 0; kt < 8; kt++)
        aw[kt] = *(const bf16x8*)(Wob + (size_t)(o_base + lm) * 256 + kt * 32 + quad * 8);

    float4v acc[8];
#pragma unroll
    for (int j = 0; j < 8; j++) acc[j] = (float4v){0.f, 0.f, 0.f, 0.f};

#pragma unroll
    for (int kt = 0; kt < 8; kt++) {
#pragma unroll
        for (int j = 0; j < 8; j++) {
            bf16x8 bf = *(const bf16x8*)(fTb + (size_t)(n_base + j * 16 + lm) * NC + kt * 32 + quad * 8);
            acc[j] = __builtin_amdgcn_mfma_f32_16x16x32_bf16(aw[kt], bf, acc[j], 0, 0, 0);
        }
    }
#pragma unroll
    for (int r = 0; r < 4; r++) {
        int o = o_base + quad * 4 + r;
        float bb = bo[o];
        size_t rowoff = ((size_t)b * NC + o) * NHW;
#pragma unroll
        for (int j = 0; j < 8; j++) {
            int n = n_base + j * 16 + lm;
            out[rowoff + n] = acc[j][r] + bb + x[rowoff + n];
        }
    }
}

// ---------- staging helper: K tile + V tile (8 DMA instructions per wave) ----------
__device__ __forceinline__ void stage_tiles(
    const u16* __restrict__ kTb, const u16* __restrict__ vNb, int kv0,
    u16* KlB, u16* VlB, int w, int lane)
{
#pragma unroll
    for (int i = 0; i < 4; i++) {
        int g = (w * 4 + i) * 64 + lane;
        int n = g >> 5, jj = g & 31, cc = jj ^ n;
        load_lds16(kTb + (size_t)(kv0 + n) * NC + cc * 8, (char*)KlB + (w * 4 + i) * 1024);
    }
#pragma unroll
    for (int i = 0; i < 4; i++) {
        int g = (w * 4 + i) * 64 + lane;
        int c = g >> 2, jj = g & 3, ck = (jj - (c >> 1)) & 3;
        load_lds16(vNb + (size_t)c * NHW + kv0 + ck * 8, (char*)VlB + (w * 4 + i) * 1024);
    }
}

// ---------- flash attention: 32 q-rows/wave (2x register reuse per LDS read) ----------
// grid 512: combo=(b*4+jc)=blockIdx&15 (XCD-local), qt=blockIdx>>4 -> 128-row q block
__global__ __launch_bounds__(256, 2) void attn_split(
    const u16* __restrict__ qT, const u16* __restrict__ kT,
    const u16* __restrict__ vN, u16* __restrict__ Opart, float* __restrict__ lpart)
{
    __shared__ u16 Kl[2][BC * 256];   // 2 x 16KB; P aliased into consumed buffer
    __shared__ u16 Vl[2][256 * BC];   // 2 x 16KB

    const int combo = blockIdx.x & 15;
    const int b  = combo >> 2;
    const int jc = combo & 3;
    const int n0 = (blockIdx.x >> 4) * 128;
    const int t = threadIdx.x;
    const int w = t >> 6, lane = t & 63;
    const int lm = lane & 15, quad = lane >> 4;

    const size_t bQ = (size_t)b * NHW * NC;
    const u16* qTb = qT + bQ;
    const u16* kTb = kT + bQ;
    const u16* vNb = vN + bQ;

    bf16x8 aq[2][8];
#pragma unroll
    for (int q = 0; q < 2; q++) {
        int qrow = n0 + w * 32 + q * 16 + lm;
#pragma unroll
        for (int kt = 0; kt < 8; kt++)
            aq[q][kt] = *(const bf16x8*)(qTb + (size_t)qrow * NC + kt * 32 + quad * 8);
    }

    float4v oacc[2][16];
#pragma unroll
    for (int q = 0; q < 2; q++)
#pragma unroll
        for (int i = 0; i < 16; i++) oacc[q][i] = (float4v){0.f, 0.f, 0.f, 0.f};
    float4v lacc[2];
    lacc[0] = (float4v){0.f, 0.f, 0.f, 0.f};
    lacc[1] = (float4v){0.f, 0.f, 0.f, 0.f};

    union { short8s s; bf16x8 b; } ou;
    ou.s = (short8s){0x3F80, 0x3F80, 0x3F80, 0x3F80, 0x3F80, 0x3F80, 0x3F80, 0x3F80};
    const bf16x8 ones = ou.b;

    const int kvbeg = jc * KVCHUNK;
    stage_tiles(kTb, vNb, kvbeg, Kl[0], Vl[0], w, lane);

    int buf = 0;
#pragma unroll 1
    for (int it = 0; it < KVCHUNK / BC; it++) {
        const int kv0 = kvbeg + it * BC;
        const int nxt = (it + 1 < KVCHUNK / BC) ? (kv0 + BC) : kvbeg;
        stage_tiles(kTb, vNb, nxt, Kl[buf ^ 1], Vl[buf ^ 1], w, lane);
        asm volatile("s_waitcnt vmcnt(8)" ::: "memory");
        __builtin_amdgcn_s_barrier();

        const u16* KlB = Kl[buf];
        const u16* VlB = Vl[buf];

        // S = Q @ K^T : 32x32 per wave; each K-frag read feeds 2 MFMAs
        float4v sf[2][2];
#pragma unroll
        for (int q = 0; q < 2; q++)
#pragma unroll
            for (int nt = 0; nt < 2; nt++) sf[q][nt] = (float4v){0.f, 0.f, 0.f, 0.f};
#pragma unroll
        for (int nt = 0; nt < 2; nt++) {
            int n = nt * 16 + lm;
#pragma unroll
            for (int kt = 0; kt < 8; kt++) {
                int cc = kt * 4 + quad;
                bf16x8 bk = *(const bf16x8*)&KlB[(n * 32 + (cc ^ n)) * 8];
                sf[0][nt] = __builtin_amdgcn_mfma_f32_16x16x32_bf16(aq[0][kt], bk, sf[0][nt], 0, 0, 0);
                sf[1][nt] = __builtin_amdgcn_mfma_f32_16x16x32_bf16(aq[1][kt], bk, sf[1][nt], 0, 0, 0);
            }
        }
        // exp (no max subtraction; logits tiny)
#pragma unroll
        for (int q = 0; q < 2; q++)
#pragma unroll
            for (int nt = 0; nt < 2; nt++)
#pragma unroll
                for (int r = 0; r < 4; r++)
                    sf[q][nt][r] = __expf(sf[q][nt][r] * 0.0625f);

        __builtin_amdgcn_s_barrier();   // K consumed -> alias P into Kl[buf]

        // P (C-layout) -> A-operand layout, truncating bf16 (bias cancels in O/l)
        u16* Pw = (u16*)Kl[buf] + w * 1024;
#pragma unroll
        for (int q = 0; q < 2; q++)
#pragma unroll
            for (int nt = 0; nt < 2; nt++) {
                int col = nt * 16 + lm;
                int cg = col >> 3, cr = col & 7;
#pragma unroll
                for (int r = 0; r < 4; r++) {
                    int row = quad * 4 + r;
                    int sg = (cg + (row >> 1)) & 3;
                    union { float f; unsigned u; } pv; pv.f = sf[q][nt][r];
                    Pw[q * 512 + row * 32 + sg * 8 + cr] = (u16)(pv.u >> 16);
                }
            }
        asm volatile("s_waitcnt lgkmcnt(0)" ::: "memory");
        bf16x8 pa0 = *(const bf16x8*)&Pw[lm * 32 + (((quad + (lm >> 1)) & 3)) * 8];
        bf16x8 pa1 = *(const bf16x8*)&Pw[512 + lm * 32 + (((quad + (lm >> 1)) & 3)) * 8];
        // row sums via ones-MFMA (replaces 16 shuffles on the LDS pipe)
        lacc[0] = __builtin_amdgcn_mfma_f32_16x16x32_bf16(pa0, ones, lacc[0], 0, 0, 0);
        lacc[1] = __builtin_amdgcn_mfma_f32_16x16x32_bf16(pa1, ones, lacc[1], 0, 0, 0);
        // PV: each V-frag read feeds 2 MFMAs
#pragma unroll
        for (int ct = 0; ct < 16; ct++) {
            int c = ct * 16 + lm;
            bf16x8 bv = *(const bf16x8*)&VlB[c * 32 + (((quad + (c >> 1)) & 3)) * 8];
            oacc[0][ct] = __builtin_amdgcn_mfma_f32_16x16x32_bf16(pa0, bv, oacc[0][ct], 0, 0, 0);
            oacc[1][ct] = __builtin_amdgcn_mfma_f32_16x16x32_bf16(pa1, bv, oacc[1][ct], 0, 0, 0);
        }
        __builtin_amdgcn_s_barrier();
        buf ^= 1;
    }

    // epilogue: partial O (bf16) + partial l
#pragma unroll
    for (int q = 0; q < 2; q++) {
        u16* Ob = Opart + ((size_t)(b * NKV + jc) * NHW + n0 + w * 32 + q * 16) * NC;
#pragma unroll
        for (int r = 0; r < 4; r++) {
            int row = quad * 4 + r;
#pragma unroll
            for (int ct = 0; ct < 16; ct++)
                Ob[(size_t)row * NC + ct * 16 + lm] = f2b(oacc[q][ct][r]);
            if (lm == 0)
                lpart[(size_t)(b * NKV + jc) * NHW + n0 + w * 32 + q * 16 + row] = lacc[q][r];
        }
    }
}

// ---------- combine kv-split partials (gT bf16) + fused gap reduce ----------
__global__ __launch_bounds__(256) void attn_combine(
    const u16* __restrict__ Opart, const float* __restrict__ lpart,
    u16* __restrict__ gT, float* __restrict__ gap)
{
    __shared__ float gsum[256];
    int t = threadIdx.x;
    gsum[t] = 0.f;
    __syncthreads();
    int b = blockIdx.y;
    int n = blockIdx.x * 8 + (t >> 5);
    int c0 = (t & 31) * 8;
    float acc[8] = {};
    float l = 0.f;
#pragma unroll
    for (int j = 0; j < NKV; j++) {
        const u16* op = Opart + ((size_t)(b * NKV + j) * NHW + n) * NC + c0;
        short8s v = *(const short8s*)op;
#pragma unroll
        for (int i = 0; i < 8; i++) acc[i] += b2f(((const u16*)&v)[i]);
        l += lpart[(size_t)(b * NKV + j) * NHW + n];
    }
    float inv = 1.0f / l;
#pragma unroll
    for (int i = 0; i < 8; i++) acc[i] *= inv;
    short8s vo;
#pragma unroll
    for (int i = 0; i < 8; i++) ((u16*)&vo)[i] = f2b(acc[i]);
    *(short8s*)(gT + ((size_t)b * NHW + n) * NC + c0) = vo;
#pragma unroll
    for (int i = 0; i < 8; i++) atomicAdd(&gsum[c0 + i], acc[i]);
    __syncthreads();
    atomicAdd(&gap[b * NC + t], gsum[t]);
}

// ---------- channel MLP (one block per batch) ----------
__global__ __launch_bounds__(256) void channel_mlp(
    const float* __restrict__ gap, const float* __restrict__ Wc1, const float* __restrict__ bc1,
    const float* __restrict__ Wc2, const float* __restrict__ bc2, float* __restrict__ cw)
{
    __shared__ float g[256];
    __shared__ float ph[32][9];
    __shared__ float h1[32];
    int t = threadIdx.x;
    int b = blockIdx.x;
    g[t] = gap[b * 256 + t] * (1.0f / 4096.0f);
    __syncthreads();
    {
        int h = t & 31, part = t >> 5;
        float s = 0.f;
        for (int c = part * 32; c < part * 32 + 32; c++) s += Wc1[h * 256 + c] * g[c];
        ph[h][part] = s;
    }
    __syncthreads();
    if (t < 32) {
        float s = bc1[t];
#pragma unroll
        for (int p = 0; p < 8; p++) s += ph[t][p];
        h1[t] = fmaxf(s, 0.f);
    }
    __syncthreads();
    float s = bc2[t];
#pragma unroll
    for (int j = 0; j < 32; j++) s += Wc2[t * 32 + j] * h1[j];
    cw[b * 256 + t] = 1.0f / (1.0f + __expf(-s));
}

extern "C" void kernel_launch(void* const* d_in, const int* in_sizes, int n_in,
                              void* d_out, int out_size, void* d_ws, size_t ws_size,
                              hipStream_t stream)
{
    const float* x   = (const float*)d_in[0];
    const float* Wq  = (const float*)d_in[1];
    const float* bq  = (const float*)d_in[2];
    const float* Wk  = (const float*)d_in[3];
    const float* bk  = (const float*)d_in[4];
    const float* Wv  = (const float*)d_in[5];
    const float* bv  = (const float*)d_in[6];
    const float* Wl  = (const float*)d_in[7];
    const float* bl  = (const float*)d_in[8];
    const float* Ws1 = (const float*)d_in[9];
    const float* bs1 = (const float*)d_in[10];
    const float* Ws2 = (const float*)d_in[11];
    const float* bs2 = (const float*)d_in[12];
    const float* Wc1 = (const float*)d_in[13];
    const float* bc1 = (const float*)d_in[14];
    const float* Wc2 = (const float*)d_in[15];
    const float* bc2 = (const float*)d_in[16];
    const float* Wo  = (const float*)d_in[17];
    const float* bo  = (const float*)d_in[18];
    float* out = (float*)d_out;

    char* ws = (char*)d_ws;
    u16* k_bf     = (u16*)(ws + OFF_KBF);
    u16* local_bf = (u16*)(ws + OFF_LBF);
    u16* gT       = (u16*)(ws + OFF_GT);
    u16* xT       = (u16*)(ws + OFF_XT);
    u16* fusedT   = (u16*)(ws + OFF_FUSEDT);
    u16* qT       = (u16*)(ws + OFF_QT);
    u16* kT       = (u16*)(ws + OFF_KT);
    u16* vN       = (u16*)(ws + OFF_VBF);
    u16* localT   = (u16*)(ws + OFF_LT);
    u16* Opart    = (u16*)(ws + OFF_OPART);
    float* lpart  = (float*)(ws + OFF_LPART);
    u16* hidT     = (u16*)(ws + OFF_HIDT);
    float* gap    = (float*)(ws + OFF_GAP);
    float* cw     = (float*)(ws + OFF_CW);
    u16* Wqb      = (u16*)(ws + OFF_WQB);
    u16* Ws1b     = (u16*)(ws + OFF_WS1B);
    u16* Ws2b     = (u16*)(ws + OFF_WS2B);
    u16* Wob      = (u16*)(ws + OFF_WOB);

    convert_weights<<<dim3(640), 256, 0, stream>>>(Wq, Ws1, Ws2, Wo, Wqb, Ws1b, Ws2b, Wob);
    dw_fused<<<dim3(8, 64, 4), 256, 0, stream>>>(x, Wk, bk, Wv, bv, Wl, bl, k_bf, vN, local_bf);
    transpose_bf<<<dim3(64, 4, 8), 256, 0, stream>>>(k_bf, local_bf, kT, localT);
    transpose_f2b<<<dim3(64, 4, 4), 256, 0, stream>>>(x, xT);
    gemm_q_mfma<<<dim3(128, 4), 256, 0, stream>>>(xT, Wqb, bq, qT);
    gemm_hid_mfma<<<dim3(128, 4), 256, 0, stream>>>(localT, Ws1b, bs1, hidT);
    attn_split<<<dim3(512), 256, 0, stream>>>(qT, kT, vN, Opart, lpart);
    hipMemsetAsync(gap, 0, NB * NC * sizeof(float), stream);
    attn_combine<<<dim3(NHW / 8, 4), 256, 0, stream>>>(Opart, lpart, gT, gap);
    channel_mlp<<<4, 256, 0, stream>>>(gap, Wc1, bc1, Wc2, bc2, cw);
    gemm_swfused_mfma<<<dim3(128, 4), 256, 0, stream>>>(hidT, Ws2b, bs2, gT, localT, cw, fusedT);
    gemm_out_mfma<<<dim3(8, 16, 4), 256, 0, stream>>>(Wob, fusedT, bo, x, out);
}

// Round 6
// 382.884 us; speedup vs baseline: 1.0534x; 1.0534x over previous
//
#include <hip/hip_runtime.h>
#include <stdint.h>

typedef unsigned short u16;
typedef __attribute__((ext_vector_type(8))) __bf16 bf16x8;
typedef __attribute__((ext_vector_type(8))) short short8s;
typedef __attribute__((ext_vector_type(4))) float float4v;
typedef __attribute__((ext_vector_type(16))) float floatx16;

// ---------- sizes ----------
static constexpr int NB = 4, NC = 256, NH = 64, NW = 64, NHW = 4096;
static constexpr int BC = 32;        // kv tile
static constexpr int NKV = 4;        // kv split factor
static constexpr int KVCHUNK = NHW / NKV;   // 1024

// ---------- workspace layout (lifetime-aliased) ----------
static constexpr size_t MB = 1ull << 20;
static constexpr size_t OFF_KBF    = 0;          // bf16 [B][C][N] 8MB (dead after transpose)
static constexpr size_t OFF_LBF    = 8 * MB;     // bf16 [B][C][N] 8MB (dead after transpose)
static constexpr size_t OFF_GT     = 0;          // bf16 [B][N][C] 8MB — overlays KBF
static constexpr size_t OFF_XT     = 16 * MB;    // bf16 [B][N][C] 8MB (dead after gemm_q)
static constexpr size_t OFF_FUSEDT = 16 * MB;    // bf16 [B][N][C] 8MB — overlays XT
static constexpr size_t OFF_QT     = 24 * MB;    // bf16 [B][N][C] 8MB
static constexpr size_t OFF_KT     = 32 * MB;    // bf16 [B][N][C] 8MB
static constexpr size_t OFF_VBF    = 40 * MB;    // bf16 [B][C][N] 8MB
static constexpr size_t OFF_LT     = 48 * MB;    // bf16 [B][N][C] 8MB (localT)
static constexpr size_t OFF_OPART  = 56 * MB;    // bf16 [B][NKV][N][C] 32MB
static constexpr size_t OFF_LPART  = 88 * MB;    // fp32 [B][NKV][N] 256KB
static constexpr size_t OFF_HIDT   = OFF_LPART + 256 * 1024;   // bf16 [B][N][64] 2MB
static constexpr size_t OFF_GAP    = OFF_HIDT + 2 * MB;        // fp32 [B][256]
static constexpr size_t OFF_CW     = OFF_GAP + 8 * 1024;       // fp32 [B][256]
static constexpr size_t OFF_WQB    = OFF_CW + 8 * 1024;        // bf16 256x256
static constexpr size_t OFF_WS1B   = OFF_WQB + 131072;         // bf16 64x256
static constexpr size_t OFF_WS2B   = OFF_WS1B + 32768;         // bf16 256x64
static constexpr size_t OFF_WOB    = OFF_WS2B + 32768;         // bf16 256x256

__device__ __forceinline__ float b2f(u16 h) {
    union { float f; unsigned u; } v; v.u = ((unsigned)h) << 16; return v.f;
}
__device__ __forceinline__ u16 f2b(float f) {
    union { float f; unsigned u; } v; v.f = f;
    unsigned r = v.u + 0x7fffu + ((v.u >> 16) & 1u);
    return (u16)(r >> 16);
}

// async global->LDS, 16B per lane; ldst wave-uniform (HW adds lane*16)
__device__ __forceinline__ void load_lds16(const void* gsrc, void* ldst) {
    __builtin_amdgcn_global_load_lds(
        (__attribute__((address_space(1))) void*)(uintptr_t)gsrc,
        (__attribute__((address_space(3))) void*)ldst,
        16, 0, 0);
}

// ---------- weight fp32->bf16 conversion ----------
__global__ __launch_bounds__(256) void convert_weights(
    const float* __restrict__ Wq, const float* __restrict__ Ws1,
    const float* __restrict__ Ws2, const float* __restrict__ Wo,
    u16* __restrict__ Wqb, u16* __restrict__ Ws1b, u16* __restrict__ Ws2b, u16* __restrict__ Wob)
{
    int id = blockIdx.x * 256 + threadIdx.x;
    if (id < 65536)        Wqb[id] = f2b(Wq[id]);
    else if (id < 81920)   Ws1b[id - 65536] = f2b(Ws1[id - 65536]);
    else if (id < 98304)   Ws2b[id - 81920] = f2b(Ws2[id - 81920]);
    else                   Wob[id - 98304] = f2b(Wo[id - 98304]);
}

// ---------- 9-tap dw conv helper (zero-pad SAME); returns 0 for invalid y ----------
__device__ __forceinline__ float dw9(const float* __restrict__ xb, const float* wgt,
                                     float bias, int y, int xx0)
{
    if ((unsigned)y > 63u) return 0.f;
    float a = bias;
#pragma unroll
    for (int dy = 0; dy < 3; dy++) {
        int yy = y + dy - 1;
        if (yy < 0 || yy > 63) continue;
#pragma unroll
        for (int dx = 0; dx < 3; dx++) {
            int xx = xx0 + dx - 1;
            if (xx < 0 || xx > 63) continue;
            a += wgt[dy * 3 + dx] * xb[yy * 64 + xx];
        }
    }
    return a;
}

// ---------- fused depthwise: k, v, local in one pass (v-row ring in LDS) ----------
__global__ __launch_bounds__(256) void dw_fused(
    const float* __restrict__ x,
    const float* __restrict__ Wk, const float* __restrict__ bk,
    const float* __restrict__ Wv, const float* __restrict__ bv,
    const float* __restrict__ Wl, const float* __restrict__ bl,
    u16* __restrict__ k_bf, u16* __restrict__ vN, u16* __restrict__ local_bf)
{
    __shared__ float vt[4][3][64];
    int t = threadIdx.x;
    int xx0 = t & 63, cl = t >> 6;
    int y0 = blockIdx.x * 8;
    int c  = blockIdx.y * 4 + cl;
    int b  = blockIdx.z;
    const float* xb = x + ((size_t)b * NC + c) * NHW;
    float wk[9], wv[9], wl[9];
#pragma unroll
    for (int i = 0; i < 9; i++) { wk[i] = Wk[c*9+i]; wv[i] = Wv[c*9+i]; wl[i] = Wl[c*9+i]; }
    float bkc = bk[c], bvc = bv[c], blc = bl[c];

    vt[cl][(y0 + 2) % 3][xx0] = dw9(xb, wv, bvc, y0 - 1, xx0);
    vt[cl][y0 % 3][xx0]       = dw9(xb, wv, bvc, y0, xx0);

    size_t base = ((size_t)b * NC + c) * NHW;
#pragma unroll 1
    for (int y = y0; y < y0 + 8; y++) {
        vt[cl][(y + 1) % 3][xx0] = dw9(xb, wv, bvc, y + 1, xx0);
        __syncthreads();
        float ak = dw9(xb, wk, bkc, y, xx0);
        float al = blc;
#pragma unroll
        for (int dy = 0; dy < 3; dy++) {
            int yy = y + dy - 1;
            const float* vrow = vt[cl][(yy + 3) % 3];
#pragma unroll
            for (int dx = 0; dx < 3; dx++) {
                int xx = xx0 + dx - 1;
                if (xx < 0 || xx > 63) continue;
                al += wl[dy * 3 + dx] * vrow[xx];
            }
        }
        size_t o = base + y * 64 + xx0;
        k_bf[o]     = f2b(ak);
        vN[o]       = f2b(vt[cl][y % 3][xx0]);
        local_bf[o] = f2b(al);
        __syncthreads();
    }
}

// ---------- bf16 transpose [C][N] -> [N][C] for k and local ----------
__global__ __launch_bounds__(256) void transpose_bf(
    const u16* __restrict__ k_bf, const u16* __restrict__ local_bf,
    u16* __restrict__ kT, u16* __restrict__ localT)
{
    __shared__ u16 tile[64][72];
    int n0 = blockIdx.x * 64, c0 = blockIdx.y * 64;
    int zb = blockIdx.z, b = zb >> 1;
    const u16* src = (zb & 1) ? local_bf : k_bf;
    u16* dst = (zb & 1) ? localT : kT;
    src += (size_t)b * NC * NHW;
    dst += (size_t)b * NHW * NC;
    int t = threadIdx.x;
    int c = t >> 2, nb = (t & 3) * 16;
    *(short8s*)&tile[c][nb]     = *(const short8s*)(src + (size_t)(c0 + c) * NHW + n0 + nb);
    *(short8s*)&tile[c][nb + 8] = *(const short8s*)(src + (size_t)(c0 + c) * NHW + n0 + nb + 8);
    __syncthreads();
    int cl = t & 63, ng = t >> 6;
#pragma unroll
    for (int j = 0; j < 16; j++) {
        int n = ng * 16 + j;
        dst[(size_t)(n0 + n) * NC + c0 + cl] = tile[cl][n];
    }
}

// ---------- fp32 [C][N] -> bf16 [N][C] transpose-convert for x ----------
__global__ __launch_bounds__(256) void transpose_f2b(
    const float* __restrict__ x, u16* __restrict__ xT)
{
    __shared__ u16 tile[64][72];
    int n0 = blockIdx.x * 64, c0 = blockIdx.y * 64, b = blockIdx.z;
    const float* src = x + (size_t)b * NC * NHW;
    u16* dst = xT + (size_t)b * NHW * NC;
    int t = threadIdx.x;
    int c = t >> 2, nb = (t & 3) * 16;
#pragma unroll
    for (int q = 0; q < 4; q++) {
        float4 v = *(const float4*)(src + (size_t)(c0 + c) * NHW + n0 + nb + q * 4);
        tile[c][nb + q * 4 + 0] = f2b(v.x);
        tile[c][nb + q * 4 + 1] = f2b(v.y);
        tile[c][nb + q * 4 + 2] = f2b(v.z);
        tile[c][nb + q * 4 + 3] = f2b(v.w);
    }
    __syncthreads();
    int cl = t & 63, ng = t >> 6;
#pragma unroll
    for (int j = 0; j < 16; j++) {
        int n = ng * 16 + j;
        dst[(size_t)(n0 + n) * NC + c0 + cl] = tile[cl][n];
    }
}

// ---------- MFMA GEMM: qT[n][cout] = xT[n][:] . Wq[cout][:] + bq ----------
__global__ __launch_bounds__(256) void gemm_q_mfma(
    const u16* __restrict__ xT, const u16* __restrict__ Wqb, const float* __restrict__ bq,
    u16* __restrict__ qT)
{
    const int t = threadIdx.x, w = t >> 6, lane = t & 63;
    const int lm = lane & 15, quad = lane >> 4;
    const int b = blockIdx.y;
    const int s_base = blockIdx.x * 32 + (w & 1) * 16;
    const int ch = (w >> 1) * 128;
    const u16* xTb = xT + (size_t)b * NHW * NC;
    u16* qTb = qT + (size_t)b * NHW * NC;

    bf16x8 aq[8];
#pragma unroll
    for (int kt = 0; kt < 8; kt++)
        aq[kt] = *(const bf16x8*)(xTb + (size_t)(s_base + lm) * NC + kt * 32 + quad * 8);

    float4v acc[8];
#pragma unroll
    for (int j = 0; j < 8; j++) acc[j] = (float4v){0.f, 0.f, 0.f, 0.f};

#pragma unroll
    for (int kt = 0; kt < 8; kt++) {
#pragma unroll
        for (int j = 0; j < 8; j++) {
            bf16x8 bw = *(const bf16x8*)(Wqb + (size_t)(ch + j * 16 + lm) * 256 + kt * 32 + quad * 8);
            acc[j] = __builtin_amdgcn_mfma_f32_16x16x32_bf16(aq[kt], bw, acc[j], 0, 0, 0);
        }
    }
#pragma unroll
    for (int j = 0; j < 8; j++) {
        int cout = ch + j * 16 + lm;
        float bb = bq[cout];
#pragma unroll
        for (int r = 0; r < 4; r++) {
            int s = s_base + quad * 4 + r;
            qTb[(size_t)s * NC + cout] = f2b(acc[j][r] + bb);
        }
    }
}

// ---------- MFMA GEMM: hidT[n][h] = relu(localT[n][:] . Ws1[h][:] + bs1) ----------
__global__ __launch_bounds__(256) void gemm_hid_mfma(
    const u16* __restrict__ localT, const u16* __restrict__ Ws1b, const float* __restrict__ bs1,
    u16* __restrict__ hidT)
{
    const int t = threadIdx.x, w = t >> 6, lane = t & 63;
    const int lm = lane & 15, quad = lane >> 4;
    const int b = blockIdx.y;
    const int s_base = blockIdx.x * 32 + (w & 1) * 16;
    const int ch = (w >> 1) * 32;
    const u16* lTb = localT + (size_t)b * NHW * NC;
    u16* hTb = hidT + (size_t)b * NHW * 64;

    bf16x8 aq[8];
#pragma unroll
    for (int kt = 0; kt < 8; kt++)
        aq[kt] = *(const bf16x8*)(lTb + (size_t)(s_base + lm) * NC + kt * 32 + quad * 8);

    float4v acc[2];
#pragma unroll
    for (int j = 0; j < 2; j++) acc[j] = (float4v){0.f, 0.f, 0.f, 0.f};

#pragma unroll
    for (int kt = 0; kt < 8; kt++) {
#pragma unroll
        for (int j = 0; j < 2; j++) {
            bf16x8 bw = *(const bf16x8*)(Ws1b + (size_t)(ch + j * 16 + lm) * 256 + kt * 32 + quad * 8);
            acc[j] = __builtin_amdgcn_mfma_f32_16x16x32_bf16(aq[kt], bw, acc[j], 0, 0, 0);
        }
    }
#pragma unroll
    for (int j = 0; j < 2; j++) {
        int h = ch + j * 16 + lm;
        float bb = bs1[h];
#pragma unroll
        for (int r = 0; r < 4; r++) {
            int s = s_base + quad * 4 + r;
            hTb[(size_t)s * 64 + h] = f2b(fmaxf(acc[j][r] + bb, 0.0f));
        }
    }
}

// ---------- MFMA GEMM + fuse: fusedT = gT*cw + localT*sigmoid(hidT.Ws2^T + bs2) ----------
__global__ __launch_bounds__(256) void gemm_swfused_mfma(
    const u16* __restrict__ hidT, const u16* __restrict__ Ws2b, const float* __restrict__ bs2,
    const u16* __restrict__ gT, const u16* __restrict__ localT, const float* __restrict__ cw,
    u16* __restrict__ fusedT)
{
    const int t = threadIdx.x, w = t >> 6, lane = t & 63;
    const int lm = lane & 15, quad = lane >> 4;
    const int b = blockIdx.y;
    const int s_base = blockIdx.x * 32 + (w & 1) * 16;
    const int ch = (w >> 1) * 128;
    const u16* hTb = hidT + (size_t)b * NHW * 64;
    const u16* lTb = localT + (size_t)b * NHW * NC;
    const u16* gTb = gT + (size_t)b * NHW * NC;
    u16* fTb = fusedT + (size_t)b * NHW * NC;

    bf16x8 aq[2];
#pragma unroll
    for (int kt = 0; kt < 2; kt++)
        aq[kt] = *(const bf16x8*)(hTb + (size_t)(s_base + lm) * 64 + kt * 32 + quad * 8);

    float4v acc[8];
#pragma unroll
    for (int j = 0; j < 8; j++) acc[j] = (float4v){0.f, 0.f, 0.f, 0.f};

#pragma unroll
    for (int kt = 0; kt < 2; kt++) {
#pragma unroll
        for (int j = 0; j < 8; j++) {
            bf16x8 bw = *(const bf16x8*)(Ws2b + (size_t)(ch + j * 16 + lm) * 64 + kt * 32 + quad * 8);
            acc[j] = __builtin_amdgcn_mfma_f32_16x16x32_bf16(aq[kt], bw, acc[j], 0, 0, 0);
        }
    }
#pragma unroll
    for (int j = 0; j < 8; j++) {
        int c = ch + j * 16 + lm;
        float bb = bs2[c];
        float cwv = cw[b * NC + c];
#pragma unroll
        for (int r = 0; r < 4; r++) {
            int s = s_base + quad * 4 + r;
            float sw = 1.0f / (1.0f + __expf(-(acc[j][r] + bb)));
            float g = b2f(gTb[(size_t)s * NC + c]);
            float lo = b2f(lTb[(size_t)s * NC + c]);
            fTb[(size_t)s * NC + c] = f2b(g * cwv + lo * sw);
        }
    }
}

// ---------- MFMA GEMM: out[o][n] = Wo[o][:] . fusedT[n][:] + bo + x ----------
__global__ __launch_bounds__(256) void gemm_out_mfma(
    const u16* __restrict__ Wob, const u16* __restrict__ fusedT, const float* __restrict__ bo,
    const float* __restrict__ x, float* __restrict__ out)
{
    const int t = threadIdx.x, w = t >> 6, lane = t & 63;
    const int lm = lane & 15, quad = lane >> 4;
    const int b = blockIdx.z;
    const int o_base = blockIdx.x * 32 + (w & 1) * 16;
    const int n_base = blockIdx.y * 256 + (w >> 1) * 128;
    const u16* fTb = fusedT + (size_t)b * NHW * NC;

    bf16x8 aw[8];
#pragma unroll
    for (int kt = 0; kt < 8; kt++)
        aw[kt] = *(const bf16x8*)(Wob + (size_t)(o_base + lm) * 256 + kt * 32 + quad * 8);

    float4v acc[8];
#pragma unroll
    for (int j = 0; j < 8; j++) acc[j] = (float4v){0.f, 0.f, 0.f, 0.f};

#pragma unroll
    for (int kt = 0; kt < 8; kt++) {
#pragma unroll
        for (int j = 0; j < 8; j++) {
            bf16x8 bf = *(const bf16x8*)(fTb + (size_t)(n_base + j * 16 + lm) * NC + kt * 32 + quad * 8);
            acc[j] = __builtin_amdgcn_mfma_f32_16x16x32_bf16(aw[kt], bf, acc[j], 0, 0, 0);
        }
    }
#pragma unroll
    for (int r = 0; r < 4; r++) {
        int o = o_base + quad * 4 + r;
        float bb = bo[o];
        size_t rowoff = ((size_t)b * NC + o) * NHW;
#pragma unroll
        for (int j = 0; j < 8; j++) {
            int n = n_base + j * 16 + lm;
            out[rowoff + n] = acc[j][r] + bb + x[rowoff + n];
        }
    }
}

// ---------- staging helper: K tile + V tile (8 DMA instructions per wave) ----------
__device__ __forceinline__ void stage_tiles(
    const u16* __restrict__ kTb, const u16* __restrict__ vNb, int kv0,
    u16* KlB, u16* VlB, int w, int lane)
{
#pragma unroll
    for (int i = 0; i < 4; i++) {
        int g = (w * 4 + i) * 64 + lane;
        int n = g >> 5, jj = g & 31, cc = jj ^ n;
        load_lds16(kTb + (size_t)(kv0 + n) * NC + cc * 8, (char*)KlB + (w * 4 + i) * 1024);
    }
#pragma unroll
    for (int i = 0; i < 4; i++) {
        int g = (w * 4 + i) * 64 + lane;
        int c = g >> 2, jj = g & 3, ck = (jj - (c >> 1)) & 3;
        load_lds16(vNb + (size_t)c * NHW + kv0 + ck * 8, (char*)VlB + (w * 4 + i) * 1024);
    }
}

// ---------- flash attention: 32x32x16 MFMA core (2x FLOP per LDS read) ----------
// grid 512: combo=(b*4+jc)=blockIdx&15 (XCD-local), qt=blockIdx>>4 -> 128-row q block.
// wave = 32 q-rows x 256 ch. 2 barriers/iter (P is wave-private, no aliasing).
__global__ __launch_bounds__(256, 2) void attn_split(
    const u16* __restrict__ qT, const u16* __restrict__ kT,
    const u16* __restrict__ vN, u16* __restrict__ Opart, float* __restrict__ lpart)
{
    __shared__ __align__(16) u16 Kl[2][BC * 256];   // 2 x 16KB
    __shared__ __align__(16) u16 Vl[2][256 * BC];   // 2 x 16KB
    __shared__ __align__(16) u16 Pl[4][32 * 40];    // wave-private P, stride 40 (16B-aligned rows)

    const int combo = blockIdx.x & 15;
    const int b  = combo >> 2;
    const int jc = combo & 3;
    const int n0 = (blockIdx.x >> 4) * 128;
    const int t = threadIdx.x;
    const int w = t >> 6, lane = t & 63;
    const int lr = lane & 31, l5 = lane >> 5;

    const size_t bQ = (size_t)b * NHW * NC;
    const u16* qTb = qT + bQ;
    const u16* kTb = kT + bQ;
    const u16* vNb = vN + bQ;

    // Q A-frags (32x32x16): A[m=lr][k=l5*8+j], 16 frags over k=256
    bf16x8 aq[16];
    {
        int qrow = n0 + w * 32 + lr;
#pragma unroll
        for (int kt = 0; kt < 16; kt++)
            aq[kt] = *(const bf16x8*)(qTb + (size_t)qrow * NC + kt * 16 + l5 * 8);
    }

    floatx16 oacc[8];
#pragma unroll
    for (int i = 0; i < 8; i++)
#pragma unroll
        for (int j = 0; j < 16; j++) oacc[i][j] = 0.f;
    float lsum = 0.f;

    const int kvbeg = jc * KVCHUNK;
    stage_tiles(kTb, vNb, kvbeg, Kl[0], Vl[0], w, lane);

    int buf = 0;
#pragma unroll 1
    for (int it = 0; it < KVCHUNK / BC; it++) {
        const int kv0 = kvbeg + it * BC;
        const int nxt = (it + 1 < KVCHUNK / BC) ? (kv0 + BC) : kvbeg;
        stage_tiles(kTb, vNb, nxt, Kl[buf ^ 1], Vl[buf ^ 1], w, lane);
        asm volatile("s_waitcnt vmcnt(8)" ::: "memory");
        __builtin_amdgcn_s_barrier();

        const u16* KlB = Kl[buf];
        const u16* VlB = Vl[buf];

        // S = Q @ K^T : 32 q x 32 kv, k=256. B[k=c][n=kv]: lane n=lr, c-granule kt*2+l5.
        floatx16 sacc;
#pragma unroll
        for (int j = 0; j < 16; j++) sacc[j] = 0.f;
#pragma unroll
        for (int kt = 0; kt < 16; kt++) {
            int gi = kt * 2 + l5;
            bf16x8 bk = *(const bf16x8*)&KlB[lr * 256 + ((gi ^ lr) & 31) * 8];
            sacc = __builtin_amdgcn_mfma_f32_32x32x16_bf16(aq[kt], bk, sacc, 0, 0, 0);
        }
        // exp (logits tiny, no max) + pack P to wave-private LDS in A-layout rows
        u16* Pw = Pl[w];
#pragma unroll
        for (int reg = 0; reg < 16; reg++) {
            float p = __expf(sacc[reg] * 0.0625f);
            int row = (reg & 3) + 8 * (reg >> 2) + 4 * l5;
            union { float f; unsigned u; } pv; pv.f = p;
            Pw[row * 40 + lr] = (u16)(pv.u >> 16);   // truncate; bias cancels in O/l
        }
        asm volatile("s_waitcnt lgkmcnt(0)" ::: "memory");
        // P A-frags: A[m=lr][k = kt*16 + l5*8 + j]
        bf16x8 pa0 = *(const bf16x8*)&Pw[lr * 40 + l5 * 8];
        bf16x8 pa1 = *(const bf16x8*)&Pw[lr * 40 + 16 + l5 * 8];
        // l partial: this lane's 16 P values (bf16->f32 exact); halves combined in epilogue
        {
            const unsigned* u0 = (const unsigned*)&pa0;
            const unsigned* u1 = (const unsigned*)&pa1;
#pragma unroll
            for (int i = 0; i < 4; i++) {
                union { unsigned u; float f; } a0, b0, a1, b1;
                a0.u = u0[i] << 16; b0.u = u0[i] & 0xffff0000u;
                a1.u = u1[i] << 16; b1.u = u1[i] & 0xffff0000u;
                lsum += (a0.f + b0.f) + (a1.f + b1.f);
            }
        }
        // PV: O += P @ V. B[k=kv][n=ch]: lane row c=ct*32+lr, kv-granule kt*2+l5.
#pragma unroll
        for (int ct = 0; ct < 8; ct++) {
            int c = ct * 32 + lr;
            int base = c * 32;
            bf16x8 bv0 = *(const bf16x8*)&VlB[base + (((l5 + (c >> 1)) & 3)) * 8];
            bf16x8 bv1 = *(const bf16x8*)&VlB[base + (((2 + l5 + (c >> 1)) & 3)) * 8];
            oacc[ct] = __builtin_amdgcn_mfma_f32_32x32x16_bf16(pa0, bv0, oacc[ct], 0, 0, 0);
            oacc[ct] = __builtin_amdgcn_mfma_f32_32x32x16_bf16(pa1, bv1, oacc[ct], 0, 0, 0);
        }
        __builtin_amdgcn_s_barrier();
        buf ^= 1;
    }

    // epilogue: unnormalized partial O (bf16) + partial l (combine divides)
    lsum += __shfl_xor(lsum, 32, 64);
    u16* Ob = Opart + ((size_t)(b * NKV + jc) * NHW + n0 + w * 32) * NC;
#pragma unroll
    for (int reg = 0; reg < 16; reg++) {
        int row = (reg & 3) + 8 * (reg >> 2) + 4 * l5;
#pragma unroll
        for (int ct = 0; ct < 8; ct++)
            Ob[(size_t)row * NC + ct * 32 + lr] = f2b(oacc[ct][reg]);
    }
    if (lane < 32)
        lpart[(size_t)(b * NKV + jc) * NHW + n0 + w * 32 + lr] = lsum;
}

// ---------- combine kv-split partials (gT bf16) + fused gap reduce ----------
__global__ __launch_bounds__(256) void attn_combine(
    const u16* __restrict__ Opart, const float* __restrict__ lpart,
    u16* __restrict__ gT, float* __restrict__ gap)
{
    __shared__ float gsum[256];
    int t = threadIdx.x;
    gsum[t] = 0.f;
    __syncthreads();
    int b = blockIdx.y;
    int n = blockIdx.x * 8 + (t >> 5);
    int c0 = (t & 31) * 8;
    float acc[8] = {};
    float l = 0.f;
#pragma unroll
    for (int j = 0; j < NKV; j++) {
        const u16* op = Opart + ((size_t)(b * NKV + j) * NHW + n) * NC + c0;
        short8s v = *(const short8s*)op;
#pragma unroll
        for (int i = 0; i < 8; i++) acc[i] += b2f(((const u16*)&v)[i]);
        l += lpart[(size_t)(b * NKV + j) * NHW + n];
    }
    float inv = 1.0f / l;
#pragma unroll
    for (int i = 0; i < 8; i++) acc[i] *= inv;
    short8s vo;
#pragma unroll
    for (int i = 0; i < 8; i++) ((u16*)&vo)[i] = f2b(acc[i]);
    *(short8s*)(gT + ((size_t)b * NHW + n) * NC + c0) = vo;
#pragma unroll
    for (int i = 0; i < 8; i++) atomicAdd(&gsum[c0 + i], acc[i]);
    __syncthreads();
    atomicAdd(&gap[b * NC + t], gsum[t]);
}

// ---------- channel MLP (one block per batch) ----------
__global__ __launch_bounds__(256) void channel_mlp(
    const float* __restrict__ gap, const float* __restrict__ Wc1, const float* __restrict__ bc1,
    const float* __restrict__ Wc2, const float* __restrict__ bc2, float* __restrict__ cw)
{
    __shared__ float g[256];
    __shared__ float ph[32][9];
    __shared__ float h1[32];
    int t = threadIdx.x;
    int b = blockIdx.x;
    g[t] = gap[b * 256 + t] * (1.0f / 4096.0f);
    __syncthreads();
    {
        int h = t & 31, part = t >> 5;
        float s = 0.f;
        for (int c = part * 32; c < part * 32 + 32; c++) s += Wc1[h * 256 + c] * g[c];
        ph[h][part] = s;
    }
    __syncthreads();
    if (t < 32) {
        float s = bc1[t];
#pragma unroll
        for (int p = 0; p < 8; p++) s += ph[t][p];
        h1[t] = fmaxf(s, 0.f);
    }
    __syncthreads();
    float s = bc2[t];
#pragma unroll
    for (int j = 0; j < 32; j++) s += Wc2[t * 32 + j] * h1[j];
    cw[b * 256 + t] = 1.0f / (1.0f + __expf(-s));
}

extern "C" void kernel_launch(void* const* d_in, const int* in_sizes, int n_in,
                              void* d_out, int out_size, void* d_ws, size_t ws_size,
                              hipStream_t stream)
{
    const float* x   = (const float*)d_in[0];
    const float* Wq  = (const float*)d_in[1];
    const float* bq  = (const float*)d_in[2];
    const float* Wk  = (const float*)d_in[3];
    const float* bk  = (const float*)d_in[4];
    const float* Wv  = (const float*)d_in[5];
    const float* bv  = (const float*)d_in[6];
    const float* Wl  = (const float*)d_in[7];
    const float* bl  = (const float*)d_in[8];
    const float* Ws1 = (const float*)d_in[9];
    const float* bs1 = (const float*)d_in[10];
    const float* Ws2 = (const float*)d_in[11];
    const float* bs2 = (const float*)d_in[12];
    const float* Wc1 = (const float*)d_in[13];
    const float* bc1 = (const float*)d_in[14];
    const float* Wc2 = (const float*)d_in[15];
    const float* bc2 = (const float*)d_in[16];
    const float* Wo  = (const float*)d_in[17];
    const float* bo  = (const float*)d_in[18];
    float* out = (float*)d_out;

    char* ws = (char*)d_ws;
    u16* k_bf     = (u16*)(ws + OFF_KBF);
    u16* local_bf = (u16*)(ws + OFF_LBF);
    u16* gT       = (u16*)(ws + OFF_GT);
    u16* xT       = (u16*)(ws + OFF_XT);
    u16* fusedT   = (u16*)(ws + OFF_FUSEDT);
    u16* qT       = (u16*)(ws + OFF_QT);
    u16* kT       = (u16*)(ws + OFF_KT);
    u16* vN       = (u16*)(ws + OFF_VBF);
    u16* localT   = (u16*)(ws + OFF_LT);
    u16* Opart    = (u16*)(ws + OFF_OPART);
    float* lpart  = (float*)(ws + OFF_LPART);
    u16* hidT     = (u16*)(ws + OFF_HIDT);
    float* gap    = (float*)(ws + OFF_GAP);
    float* cw     = (float*)(ws + OFF_CW);
    u16* Wqb      = (u16*)(ws + OFF_WQB);
    u16* Ws1b     = (u16*)(ws + OFF_WS1B);
    u16* Ws2b     = (u16*)(ws + OFF_WS2B);
    u16* Wob      = (u16*)(ws + OFF_WOB);

    convert_weights<<<dim3(640), 256, 0, stream>>>(Wq, Ws1, Ws2, Wo, Wqb, Ws1b, Ws2b, Wob);
    dw_fused<<<dim3(8, 64, 4), 256, 0, stream>>>(x, Wk, bk, Wv, bv, Wl, bl, k_bf, vN, local_bf);
    transpose_bf<<<dim3(64, 4, 8), 256, 0, stream>>>(k_bf, local_bf, kT, localT);
    transpose_f2b<<<dim3(64, 4, 4), 256, 0, stream>>>(x, xT);
    gemm_q_mfma<<<dim3(128, 4), 256, 0, stream>>>(xT, Wqb, bq, qT);
    gemm_hid_mfma<<<dim3(128, 4), 256, 0, stream>>>(localT, Ws1b, bs1, hidT);
    attn_split<<<dim3(512), 256, 0, stream>>>(qT, kT, vN, Opart, lpart);
    hipMemsetAsync(gap, 0, NB * NC * sizeof(float), stream);
    attn_combine<<<dim3(NHW / 8, 4), 256, 0, stream>>>(Opart, lpart, gT, gap);
    channel_mlp<<<4, 256, 0, stream>>>(gap, Wc1, bc1, Wc2, bc2, cw);
    gemm_swfused_mfma<<<dim3(128, 4), 256, 0, stream>>>(hidT, Ws2b, bs2, gT, localT, cw, fusedT);
    gemm_out_mfma<<<dim3(8, 16, 4), 256, 0, stream>>>(Wob, fusedT, bo, x, out);
}

// Round 7
// 373.475 us; speedup vs baseline: 1.0799x; 1.0252x over previous
//
#include <hip/hip_runtime.h>
#include <stdint.h>

typedef unsigned short u16;
typedef __attribute__((ext_vector_type(8))) __bf16 bf16x8;
typedef __attribute__((ext_vector_type(8))) short short8s;
typedef __attribute__((ext_vector_type(4))) float float4v;
typedef __attribute__((ext_vector_type(16))) float floatx16;

// ---------- sizes ----------
static constexpr int NB = 4, NC = 256, NH = 64, NW = 64, NHW = 4096;
static constexpr int BC = 32;        // kv tile
static constexpr int NKV = 4;        // kv split factor
static constexpr int KVCHUNK = NHW / NKV;   // 1024

// ---------- workspace layout (lifetime-aliased) ----------
static constexpr size_t MB = 1ull << 20;
static constexpr size_t OFF_KBF    = 0;          // bf16 [B][C][N] 8MB (dead after transpose)
static constexpr size_t OFF_LBF    = 8 * MB;     // bf16 [B][C][N] 8MB (dead after transpose)
static constexpr size_t OFF_GT     = 0;          // bf16 [B][N][C] 8MB — overlays KBF
static constexpr size_t OFF_XT     = 16 * MB;    // bf16 [B][N][C] 8MB (dead after gemm_qhid)
static constexpr size_t OFF_FUSEDT = 16 * MB;    // bf16 [B][N][C] 8MB — overlays XT
static constexpr size_t OFF_QT     = 24 * MB;    // bf16 [B][N][C] 8MB
static constexpr size_t OFF_KT     = 32 * MB;    // bf16 [B][N][C] 8MB
static constexpr size_t OFF_VBF    = 40 * MB;    // bf16 [B][C][N] 8MB
static constexpr size_t OFF_LT     = 48 * MB;    // bf16 [B][N][C] 8MB (localT)
static constexpr size_t OFF_OPART  = 56 * MB;    // bf16 [B][NKV][N][C] 32MB
static constexpr size_t OFF_LPART  = 88 * MB;    // fp32 [B][NKV][N] 256KB
static constexpr size_t OFF_HIDT   = OFF_LPART + 256 * 1024;   // bf16 [B][N][64] 2MB
static constexpr size_t OFF_GAP    = OFF_HIDT + 2 * MB;        // fp32 [B][256]
static constexpr size_t OFF_WQB    = OFF_GAP + 8 * 1024;       // bf16 256x256
static constexpr size_t OFF_WS1B   = OFF_WQB + 131072;         // bf16 64x256
static constexpr size_t OFF_WS2B   = OFF_WS1B + 32768;         // bf16 256x64
static constexpr size_t OFF_WOB    = OFF_WS2B + 32768;         // bf16 256x256

__device__ __forceinline__ float b2f(u16 h) {
    union { float f; unsigned u; } v; v.u = ((unsigned)h) << 16; return v.f;
}
__device__ __forceinline__ u16 f2b(float f) {
    union { float f; unsigned u; } v; v.f = f;
    unsigned r = v.u + 0x7fffu + ((v.u >> 16) & 1u);
    return (u16)(r >> 16);
}

// async global->LDS, 16B per lane; ldst wave-uniform (HW adds lane*16)
__device__ __forceinline__ void load_lds16(const void* gsrc, void* ldst) {
    __builtin_amdgcn_global_load_lds(
        (__attribute__((address_space(1))) void*)(uintptr_t)gsrc,
        (__attribute__((address_space(3))) void*)ldst,
        16, 0, 0);
}

// ---------- 9-tap dw conv helper (zero-pad SAME); returns 0 for invalid y ----------
__device__ __forceinline__ float dw9(const float* __restrict__ xb, const float* wgt,
                                     float bias, int y, int xx0)
{
    if ((unsigned)y > 63u) return 0.f;
    float a = bias;
#pragma unroll
    for (int dy = 0; dy < 3; dy++) {
        int yy = y + dy - 1;
        if (yy < 0 || yy > 63) continue;
#pragma unroll
        for (int dx = 0; dx < 3; dx++) {
            int xx = xx0 + dx - 1;
            if (xx < 0 || xx > 63) continue;
            a += wgt[dy * 3 + dx] * xb[yy * 64 + xx];
        }
    }
    return a;
}

// ---------- prep mega-kernel: convert_weights + gap-zero | dw_fused | transpose_f2b ----------
// zone A: blocks [0,644)     — weight fp32->bf16 + gap zero
// zone B: blocks [644,2692)  — fused depthwise k/v/local (bf16 [C][N] outputs)
// zone C: blocks [2692,3716) — x fp32 [C][N] -> bf16 [N][C]
__global__ __launch_bounds__(256) void prep(
    const float* __restrict__ x,
    const float* __restrict__ Wq, const float* __restrict__ Ws1,
    const float* __restrict__ Ws2, const float* __restrict__ Wo,
    const float* __restrict__ Wk, const float* __restrict__ bk,
    const float* __restrict__ Wv, const float* __restrict__ bv,
    const float* __restrict__ Wl, const float* __restrict__ bl,
    u16* __restrict__ Wqb, u16* __restrict__ Ws1b, u16* __restrict__ Ws2b, u16* __restrict__ Wob,
    float* __restrict__ gap,
    u16* __restrict__ k_bf, u16* __restrict__ vN, u16* __restrict__ local_bf,
    u16* __restrict__ xT)
{
    __shared__ __align__(16) unsigned char pshm[9216];
    const int bid = blockIdx.x;
    const int t = threadIdx.x;

    if (bid < 644) {
        int id = bid * 256 + t;
        if (id < 65536)        Wqb[id] = f2b(Wq[id]);
        else if (id < 81920)   Ws1b[id - 65536] = f2b(Ws1[id - 65536]);
        else if (id < 98304)   Ws2b[id - 81920] = f2b(Ws2[id - 81920]);
        else if (id < 163840)  Wob[id - 98304] = f2b(Wo[id - 98304]);
        else if (id < 164864)  gap[id - 163840] = 0.f;
        return;
    }
    if (bid < 2692) {
        // ---- fused depthwise ----
        float (*vt)[3][64] = reinterpret_cast<float (*)[3][64]>(pshm);
        int l = bid - 644;
        int xx0 = t & 63, cl = t >> 6;
        int y0 = (l & 7) * 8;
        int c  = ((l >> 3) & 63) * 4 + cl;
        int b  = l >> 9;
        const float* xb = x + ((size_t)b * NC + c) * NHW;
        float wk[9], wv[9], wl[9];
#pragma unroll
        for (int i = 0; i < 9; i++) { wk[i] = Wk[c*9+i]; wv[i] = Wv[c*9+i]; wl[i] = Wl[c*9+i]; }
        float bkc = bk[c], bvc = bv[c], blc = bl[c];

        vt[cl][(y0 + 2) % 3][xx0] = dw9(xb, wv, bvc, y0 - 1, xx0);
        vt[cl][y0 % 3][xx0]       = dw9(xb, wv, bvc, y0, xx0);

        size_t base = ((size_t)b * NC + c) * NHW;
#pragma unroll 1
        for (int y = y0; y < y0 + 8; y++) {
            vt[cl][(y + 1) % 3][xx0] = dw9(xb, wv, bvc, y + 1, xx0);
            __syncthreads();
            float ak = dw9(xb, wk, bkc, y, xx0);
            float al = blc;
#pragma unroll
            for (int dy = 0; dy < 3; dy++) {
                int yy = y + dy - 1;
                const float* vrow = vt[cl][(yy + 3) % 3];
#pragma unroll
                for (int dx = 0; dx < 3; dx++) {
                    int xx = xx0 + dx - 1;
                    if (xx < 0 || xx > 63) continue;
                    al += wl[dy * 3 + dx] * vrow[xx];
                }
            }
            size_t o = base + y * 64 + xx0;
            k_bf[o]     = f2b(ak);
            vN[o]       = f2b(vt[cl][y % 3][xx0]);
            local_bf[o] = f2b(al);
            __syncthreads();
        }
        return;
    }
    {
        // ---- transpose-convert x ----
        u16 (*tile)[72] = reinterpret_cast<u16 (*)[72]>(pshm);
        int l = bid - 2692;
        int n0 = (l & 63) * 64;
        int c0 = ((l >> 6) & 3) * 64;
        int b  = l >> 8;
        const float* src = x + (size_t)b * NC * NHW;
        u16* dst = xT + (size_t)b * NHW * NC;
        int c = t >> 2, nb = (t & 3) * 16;
#pragma unroll
        for (int q = 0; q < 4; q++) {
            float4 v = *(const float4*)(src + (size_t)(c0 + c) * NHW + n0 + nb + q * 4);
            tile[c][nb + q * 4 + 0] = f2b(v.x);
            tile[c][nb + q * 4 + 1] = f2b(v.y);
            tile[c][nb + q * 4 + 2] = f2b(v.z);
            tile[c][nb + q * 4 + 3] = f2b(v.w);
        }
        __syncthreads();
        int cl = t & 63, ng = t >> 6;
#pragma unroll
        for (int j = 0; j < 16; j++) {
            int n = ng * 16 + j;
            dst[(size_t)(n0 + n) * NC + c0 + cl] = tile[cl][n];
        }
    }
}

// ---------- bf16 transpose [C][N] -> [N][C] for k and local ----------
__global__ __launch_bounds__(256) void transpose_bf(
    const u16* __restrict__ k_bf, const u16* __restrict__ local_bf,
    u16* __restrict__ kT, u16* __restrict__ localT)
{
    __shared__ u16 tile[64][72];
    int n0 = blockIdx.x * 64, c0 = blockIdx.y * 64;
    int zb = blockIdx.z, b = zb >> 1;
    const u16* src = (zb & 1) ? local_bf : k_bf;
    u16* dst = (zb & 1) ? localT : kT;
    src += (size_t)b * NC * NHW;
    dst += (size_t)b * NHW * NC;
    int t = threadIdx.x;
    int c = t >> 2, nb = (t & 3) * 16;
    *(short8s*)&tile[c][nb]     = *(const short8s*)(src + (size_t)(c0 + c) * NHW + n0 + nb);
    *(short8s*)&tile[c][nb + 8] = *(const short8s*)(src + (size_t)(c0 + c) * NHW + n0 + nb + 8);
    __syncthreads();
    int cl = t & 63, ng = t >> 6;
#pragma unroll
    for (int j = 0; j < 16; j++) {
        int n = ng * 16 + j;
        dst[(size_t)(n0 + n) * NC + c0 + cl] = tile[cl][n];
    }
}

// ---------- fused MFMA GEMMs: qT = xT.Wq^T + bq  |  hidT = relu(localT.Ws1^T + bs1) ----------
__global__ __launch_bounds__(256) void gemm_qhid(
    const u16* __restrict__ xT, const u16* __restrict__ Wqb, const float* __restrict__ bq,
    u16* __restrict__ qT,
    const u16* __restrict__ localT, const u16* __restrict__ Ws1b, const float* __restrict__ bs1,
    u16* __restrict__ hidT)
{
    const int t = threadIdx.x, w = t >> 6, lane = t & 63;
    const int lm = lane & 15, quad = lane >> 4;
    const int zone = blockIdx.x >> 9;           // 0: q, 1: hid
    const int l = blockIdx.x & 511;
    const int b = l >> 7;
    const int s_base = (l & 127) * 32 + (w & 1) * 16;

    if (zone == 0) {
        const int ch = (w >> 1) * 128;
        const u16* xTb = xT + (size_t)b * NHW * NC;
        u16* qTb = qT + (size_t)b * NHW * NC;
        bf16x8 aq[8];
#pragma unroll
        for (int kt = 0; kt < 8; kt++)
            aq[kt] = *(const bf16x8*)(xTb + (size_t)(s_base + lm) * NC + kt * 32 + quad * 8);
        float4v acc[8];
#pragma unroll
        for (int j = 0; j < 8; j++) acc[j] = (float4v){0.f, 0.f, 0.f, 0.f};
#pragma unroll
        for (int kt = 0; kt < 8; kt++) {
#pragma unroll
            for (int j = 0; j < 8; j++) {
                bf16x8 bw = *(const bf16x8*)(Wqb + (size_t)(ch + j * 16 + lm) * 256 + kt * 32 + quad * 8);
                acc[j] = __builtin_amdgcn_mfma_f32_16x16x32_bf16(aq[kt], bw, acc[j], 0, 0, 0);
            }
        }
#pragma unroll
        for (int j = 0; j < 8; j++) {
            int cout = ch + j * 16 + lm;
            float bb = bq[cout];
#pragma unroll
            for (int r = 0; r < 4; r++) {
                int s = s_base + quad * 4 + r;
                qTb[(size_t)s * NC + cout] = f2b(acc[j][r] + bb);
            }
        }
    } else {
        const int ch = (w >> 1) * 32;
        const u16* lTb = localT + (size_t)b * NHW * NC;
        u16* hTb = hidT + (size_t)b * NHW * 64;
        bf16x8 aq[8];
#pragma unroll
        for (int kt = 0; kt < 8; kt++)
            aq[kt] = *(const bf16x8*)(lTb + (size_t)(s_base + lm) * NC + kt * 32 + quad * 8);
        float4v acc[2];
#pragma unroll
        for (int j = 0; j < 2; j++) acc[j] = (float4v){0.f, 0.f, 0.f, 0.f};
#pragma unroll
        for (int kt = 0; kt < 8; kt++) {
#pragma unroll
            for (int j = 0; j < 2; j++) {
                bf16x8 bw = *(const bf16x8*)(Ws1b + (size_t)(ch + j * 16 + lm) * 256 + kt * 32 + quad * 8);
                acc[j] = __builtin_amdgcn_mfma_f32_16x16x32_bf16(aq[kt], bw, acc[j], 0, 0, 0);
            }
        }
#pragma unroll
        for (int j = 0; j < 2; j++) {
            int h = ch + j * 16 + lm;
            float bb = bs1[h];
#pragma unroll
            for (int r = 0; r < 4; r++) {
                int s = s_base + quad * 4 + r;
                hTb[(size_t)s * 64 + h] = f2b(fmaxf(acc[j][r] + bb, 0.0f));
            }
        }
    }
}

// ---------- staging helper: K tile + V tile (8 DMA instructions per wave) ----------
__device__ __forceinline__ void stage_tiles(
    const u16* __restrict__ kTb, const u16* __restrict__ vNb, int kv0,
    u16* KlB, u16* VlB, int w, int lane)
{
#pragma unroll
    for (int i = 0; i < 4; i++) {
        int g = (w * 4 + i) * 64 + lane;
        int n = g >> 5, jj = g & 31, cc = jj ^ n;
        load_lds16(kTb + (size_t)(kv0 + n) * NC + cc * 8, (char*)KlB + (w * 4 + i) * 1024);
    }
#pragma unroll
    for (int i = 0; i < 4; i++) {
        int g = (w * 4 + i) * 64 + lane;
        int c = g >> 2, jj = g & 3, ck = (jj - (c >> 1)) & 3;
        load_lds16(vNb + (size_t)c * NHW + kv0 + ck * 8, (char*)VlB + (w * 4 + i) * 1024);
    }
}

// ---------- flash attention: S^T = K.Q^T formulation, P via half-wave shuffle ----------
// grid 512: combo=(b*4+jc)=blockIdx&15 (XCD-local), qt=blockIdx>>4 -> 128-row q block.
// S^T C-layout puts q in the lane dim -> P is A-operand-shaped up to a l5-half exchange
// (4 shfl_xor of packed bf16 pairs). No P LDS round-trip, no mid barrier, true row sums.
__global__ __launch_bounds__(256, 2) void attn_split(
    const u16* __restrict__ qT, const u16* __restrict__ kT,
    const u16* __restrict__ vN, u16* __restrict__ Opart, float* __restrict__ lpart)
{
    __shared__ __align__(16) u16 Kl[2][BC * 256];   // 2 x 16KB
    __shared__ __align__(16) u16 Vl[2][256 * BC];   // 2 x 16KB

    const int combo = blockIdx.x & 15;
    const int b  = combo >> 2;
    const int jc = combo & 3;
    const int n0 = (blockIdx.x >> 4) * 128;
    const int t = threadIdx.x;
    const int w = t >> 6, lane = t & 63;
    const int lr = lane & 31, l5 = lane >> 5;

    const size_t bQ = (size_t)b * NHW * NC;
    const u16* qTb = qT + bQ;
    const u16* kTb = kT + bQ;
    const u16* vNb = vN + bQ;

    // Q frags (used as B-operand of S^T): B[k=c][n=q=lr], k granule kt*16 + l5*8
    bf16x8 aq[16];
    {
        int qrow = n0 + w * 32 + lr;
#pragma unroll
        for (int kt = 0; kt < 16; kt++)
            aq[kt] = *(const bf16x8*)(qTb + (size_t)qrow * NC + kt * 16 + l5 * 8);
    }

    floatx16 oacc[8];
#pragma unroll
    for (int i = 0; i < 8; i++)
#pragma unroll
        for (int j = 0; j < 16; j++) oacc[i][j] = 0.f;
    float lsum = 0.f;

    const int kvbeg = jc * KVCHUNK;
    stage_tiles(kTb, vNb, kvbeg, Kl[0], Vl[0], w, lane);

    int buf = 0;
#pragma unroll 1
    for (int it = 0; it < KVCHUNK / BC; it++) {
        const int kv0 = kvbeg + it * BC;
        const int nxt = (it + 1 < KVCHUNK / BC) ? (kv0 + BC) : kvbeg;
        stage_tiles(kTb, vNb, nxt, Kl[buf ^ 1], Vl[buf ^ 1], w, lane);
        asm volatile("s_waitcnt vmcnt(8)" ::: "memory");
        __builtin_amdgcn_s_barrier();

        const u16* KlB = Kl[buf];
        const u16* VlB = Vl[buf];

        // S^T[kv][q]: A = K[m=kv=lr][k=c], B = Q^T (aq regs). col=q=lr, row=kv in regs.
        floatx16 sacc;
#pragma unroll
        for (int j = 0; j < 16; j++) sacc[j] = 0.f;
#pragma unroll
        for (int kt = 0; kt < 16; kt++) {
            int gi = kt * 2 + l5;
            bf16x8 ak = *(const bf16x8*)&KlB[lr * 256 + ((gi ^ lr) & 31) * 8];
            sacc = __builtin_amdgcn_mfma_f32_32x32x16_bf16(ak, aq[kt], sacc, 0, 0, 0);
        }
        // exp + row-sum (true per-q: this lane holds 16 kv values of q=lr) + pack bf16 pairs
        unsigned pk[8];
#pragma unroll
        for (int g2 = 0; g2 < 8; g2++) {
            float p0 = __expf(sacc[g2 * 2 + 0] * 0.0625f);
            float p1 = __expf(sacc[g2 * 2 + 1] * 0.0625f);
            lsum += p0 + p1;
            union { float f; unsigned u; } a, bb;
            a.f = p0; bb.f = p1;
            pk[g2] = (bb.u & 0xffff0000u) | (a.u >> 16);   // truncate; bias cancels in O/l
        }
        // half-wave exchange -> P A-frags: A[m=q=lr][k=kv=16*kt2 + l5*8 + j]
        unsigned rA = (unsigned)__shfl_xor((int)(l5 ? pk[0] : pk[2]), 32, 64);
        unsigned rB = (unsigned)__shfl_xor((int)(l5 ? pk[1] : pk[3]), 32, 64);
        unsigned rC = (unsigned)__shfl_xor((int)(l5 ? pk[4] : pk[6]), 32, 64);
        unsigned rD = (unsigned)__shfl_xor((int)(l5 ? pk[5] : pk[7]), 32, 64);
        union { unsigned u[4]; bf16x8 v; } f0, f1;
        f0.u[0] = l5 ? rA : pk[0];  f0.u[1] = l5 ? rB : pk[1];
        f0.u[2] = l5 ? pk[2] : rA;  f0.u[3] = l5 ? pk[3] : rB;
        f1.u[0] = l5 ? rC : pk[4];  f1.u[1] = l5 ? rD : pk[5];
        f1.u[2] = l5 ? pk[6] : rC;  f1.u[3] = l5 ? pk[7] : rD;

        // PV: O += P @ V. B = V^T frag from Vl [c][kv].
#pragma unroll
        for (int ct = 0; ct < 8; ct++) {
            int c = ct * 32 + lr;
            int vb = c * 32;
            bf16x8 bv0 = *(const bf16x8*)&VlB[vb + (((l5 + (c >> 1)) & 3)) * 8];
            bf16x8 bv1 = *(const bf16x8*)&VlB[vb + (((2 + l5 + (c >> 1)) & 3)) * 8];
            oacc[ct] = __builtin_amdgcn_mfma_f32_32x32x16_bf16(f0.v, bv0, oacc[ct], 0, 0, 0);
            oacc[ct] = __builtin_amdgcn_mfma_f32_32x32x16_bf16(f1.v, bv1, oacc[ct], 0, 0, 0);
        }
        __builtin_amdgcn_s_barrier();
        buf ^= 1;
    }

    // epilogue: unnormalized partial O (bf16) + partial l (combine divides)
    lsum += __shfl_xor(lsum, 32, 64);
    u16* Ob = Opart + ((size_t)(b * NKV + jc) * NHW + n0 + w * 32) * NC;
#pragma unroll
    for (int reg = 0; reg < 16; reg++) {
        int row = (reg & 3) + 8 * (reg >> 2) + 4 * l5;
#pragma unroll
        for (int ct = 0; ct < 8; ct++)
            Ob[(size_t)row * NC + ct * 32 + lr] = f2b(oacc[ct][reg]);
    }
    if (lane < 32)
        lpart[(size_t)(b * NKV + jc) * NHW + n0 + w * 32 + lr] = lsum;
}

// ---------- combine kv-split partials (gT bf16) + fused gap reduce ----------
__global__ __launch_bounds__(256) void attn_combine(
    const u16* __restrict__ Opart, const float* __restrict__ lpart,
    u16* __restrict__ gT, float* __restrict__ gap)
{
    __shared__ float gsum[256];
    int t = threadIdx.x;
    gsum[t] = 0.f;
    __syncthreads();
    int b = blockIdx.y;
    int n = blockIdx.x * 8 + (t >> 5);
    int c0 = (t & 31) * 8;
    float acc[8] = {};
    float l = 0.f;
#pragma unroll
    for (int j = 0; j < NKV; j++) {
        const u16* op = Opart + ((size_t)(b * NKV + j) * NHW + n) * NC + c0;
        short8s v = *(const short8s*)op;
#pragma unroll
        for (int i = 0; i < 8; i++) acc[i] += b2f(((const u16*)&v)[i]);
        l += lpart[(size_t)(b * NKV + j) * NHW + n];
    }
    float inv = 1.0f / l;
#pragma unroll
    for (int i = 0; i < 8; i++) acc[i] *= inv;
    short8s vo;
#pragma unroll
    for (int i = 0; i < 8; i++) ((u16*)&vo)[i] = f2b(acc[i]);
    *(short8s*)(gT + ((size_t)b * NHW + n) * NC + c0) = vo;
#pragma unroll
    for (int i = 0; i < 8; i++) atomicAdd(&gsum[c0 + i], acc[i]);
    __syncthreads();
    atomicAdd(&gap[b * NC + t], gsum[t]);
}

// ---------- MFMA GEMM + inline channel-MLP + fuse ----------
// fusedT = gT*cw + localT*sigmoid(hidT.Ws2^T + bs2); cw computed per-block from gap
__global__ __launch_bounds__(256) void gemm_swfused_mfma(
    const u16* __restrict__ hidT, const u16* __restrict__ Ws2b, const float* __restrict__ bs2,
    const u16* __restrict__ gT, const u16* __restrict__ localT,
    const float* __restrict__ gap,
    const float* __restrict__ Wc1, const float* __restrict__ bc1,
    const float* __restrict__ Wc2, const float* __restrict__ bc2,
    u16* __restrict__ fusedT)
{
    __shared__ float g[256], h1[32], cwl[256];
    __shared__ float ph[32][9];
    const int t = threadIdx.x, w = t >> 6, lane = t & 63;
    const int lm = lane & 15, quad = lane >> 4;
    const int b = blockIdx.y;

    // inline channel MLP (16K MACs, negligible)
    g[t] = gap[b * 256 + t] * (1.0f / 4096.0f);
    __syncthreads();
    {
        int h = t & 31, part = t >> 5;
        float s = 0.f;
        for (int c = part * 32; c < part * 32 + 32; c++) s += Wc1[h * 256 + c] * g[c];
        ph[h][part] = s;
    }
    __syncthreads();
    if (t < 32) {
        float s = bc1[t];
#pragma unroll
        for (int p = 0; p < 8; p++) s += ph[t][p];
        h1[t] = fmaxf(s, 0.f);
    }
    __syncthreads();
    {
        float s = bc2[t];
#pragma unroll
        for (int j = 0; j < 32; j++) s += Wc2[t * 32 + j] * h1[j];
        cwl[t] = 1.0f / (1.0f + __expf(-s));
    }
    __syncthreads();

    const int s_base = blockIdx.x * 32 + (w & 1) * 16;
    const int ch = (w >> 1) * 128;
    const u16* hTb = hidT + (size_t)b * NHW * 64;
    const u16* lTb = localT + (size_t)b * NHW * NC;
    const u16* gTb = gT + (size_t)b * NHW * NC;
    u16* fTb = fusedT + (size_t)b * NHW * NC;

    bf16x8 aq[2];
#pragma unroll
    for (int kt = 0; kt < 2; kt++)
        aq[kt] = *(const bf16x8*)(hTb + (size_t)(s_base + lm) * 64 + kt * 32 + quad * 8);

    float4v acc[8];
#pragma unroll
    for (int j = 0; j < 8; j++) acc[j] = (float4v){0.f, 0.f, 0.f, 0.f};

#pragma unroll
    for (int kt = 0; kt < 2; kt++) {
#pragma unroll
        for (int j = 0; j < 8; j++) {
            bf16x8 bw = *(const bf16x8*)(Ws2b + (size_t)(ch + j * 16 + lm) * 64 + kt * 32 + quad * 8);
            acc[j] = __builtin_amdgcn_mfma_f32_16x16x32_bf16(aq[kt], bw, acc[j], 0, 0, 0);
        }
    }
#pragma unroll
    for (int j = 0; j < 8; j++) {
        int c = ch + j * 16 + lm;
        float bb = bs2[c];
        float cwv = cwl[c];
#pragma unroll
        for (int r = 0; r < 4; r++) {
            int s = s_base + quad * 4 + r;
            float sw = 1.0f / (1.0f + __expf(-(acc[j][r] + bb)));
            float gg = b2f(gTb[(size_t)s * NC + c]);
            float lo = b2f(lTb[(size_t)s * NC + c]);
            fTb[(size_t)s * NC + c] = f2b(gg * cwv + lo * sw);
        }
    }
}

// ---------- MFMA GEMM: out[o][n] = Wo[o][:] . fusedT[n][:] + bo + x ----------
__global__ __launch_bounds__(256) void gemm_out_mfma(
    const u16* __restrict__ Wob, const u16* __restrict__ fusedT, const float* __restrict__ bo,
    const float* __restrict__ x, float* __restrict__ out)
{
    const int t = threadIdx.x, w = t >> 6, lane = t & 63;
    const int lm = lane & 15, quad = lane >> 4;
    const int b = blockIdx.z;
    const int o_base = blockIdx.x * 32 + (w & 1) * 16;
    const int n_base = blockIdx.y * 256 + (w >> 1) * 128;
    const u16* fTb = fusedT + (size_t)b * NHW * NC;

    bf16x8 aw[8];
#pragma unroll
    for (int kt = 0; kt < 8; kt++)
        aw[kt] = *(const bf16x8*)(Wob + (size_t)(o_base + lm) * 256 + kt * 32 + quad * 8);

    float4v acc[8];
#pragma unroll
    for (int j = 0; j < 8; j++) acc[j] = (float4v){0.f, 0.f, 0.f, 0.f};

#pragma unroll
    for (int kt = 0; kt < 8; kt++) {
#pragma unroll
        for (int j = 0; j < 8; j++) {
            bf16x8 bf = *(const bf16x8*)(fTb + (size_t)(n_base + j * 16 + lm) * NC + kt * 32 + quad * 8);
            acc[j] = __builtin_amdgcn_mfma_f32_16x16x32_bf16(aw[kt], bf, acc[j], 0, 0, 0);
        }
    }
#pragma unroll
    for (int r = 0; r < 4; r++) {
        int o = o_base + quad * 4 + r;
        float bb = bo[o];
        size_t rowoff = ((size_t)b * NC + o) * NHW;
#pragma unroll
        for (int j = 0; j < 8; j++) {
            int n = n_base + j * 16 + lm;
            out[rowoff + n] = acc[j][r] + bb + x[rowoff + n];
        }
    }
}

extern "C" void kernel_launch(void* const* d_in, const int* in_sizes, int n_in,
                              void* d_out, int out_size, void* d_ws, size_t ws_size,
                              hipStream_t stream)
{
    const float* x   = (const float*)d_in[0];
    const float* Wq  = (const float*)d_in[1];
    const float* bq  = (const float*)d_in[2];
    const float* Wk  = (const float*)d_in[3];
    const float* bk  = (const float*)d_in[4];
    const float* Wv  = (const float*)d_in[5];
    const float* bv  = (const float*)d_in[6];
    const float* Wl  = (const float*)d_in[7];
    const float* bl  = (const float*)d_in[8];
    const float* Ws1 = (const float*)d_in[9];
    const float* bs1 = (const float*)d_in[10];
    const float* Ws2 = (const float*)d_in[11];
    const float* bs2 = (const float*)d_in[12];
    const float* Wc1 = (const float*)d_in[13];
    const float* bc1 = (const float*)d_in[14];
    const float* Wc2 = (const float*)d_in[15];
    const float* bc2 = (const float*)d_in[16];
    const float* Wo  = (const float*)d_in[17];
    const float* bo  = (const float*)d_in[18];
    float* out = (float*)d_out;

    char* ws = (char*)d_ws;
    u16* k_bf     = (u16*)(ws + OFF_KBF);
    u16* local_bf = (u16*)(ws + OFF_LBF);
    u16* gT       = (u16*)(ws + OFF_GT);
    u16* xT       = (u16*)(ws + OFF_XT);
    u16* fusedT   = (u16*)(ws + OFF_FUSEDT);
    u16* qT       = (u16*)(ws + OFF_QT);
    u16* kT       = (u16*)(ws + OFF_KT);
    u16* vN       = (u16*)(ws + OFF_VBF);
    u16* localT   = (u16*)(ws + OFF_LT);
    u16* Opart    = (u16*)(ws + OFF_OPART);
    float* lpart  = (float*)(ws + OFF_LPART);
    u16* hidT     = (u16*)(ws + OFF_HIDT);
    float* gap    = (float*)(ws + OFF_GAP);
    u16* Wqb      = (u16*)(ws + OFF_WQB);
    u16* Ws1b     = (u16*)(ws + OFF_WS1B);
    u16* Ws2b     = (u16*)(ws + OFF_WS2B);
    u16* Wob      = (u16*)(ws + OFF_WOB);

    prep<<<dim3(3716), 256, 0, stream>>>(x, Wq, Ws1, Ws2, Wo, Wk, bk, Wv, bv, Wl, bl,
                                         Wqb, Ws1b, Ws2b, Wob, gap, k_bf, vN, local_bf, xT);
    transpose_bf<<<dim3(64, 4, 8), 256, 0, stream>>>(k_bf, local_bf, kT, localT);
    gemm_qhid<<<dim3(1024), 256, 0, stream>>>(xT, Wqb, bq, qT, localT, Ws1b, bs1, hidT);
    attn_split<<<dim3(512), 256, 0, stream>>>(qT, kT, vN, Opart, lpart);
    attn_combine<<<dim3(NHW / 8, 4), 256, 0, stream>>>(Opart, lpart, gT, gap);
    gemm_swfused_mfma<<<dim3(128, 4), 256, 0, stream>>>(hidT, Ws2b, bs2, gT, localT,
                                                        gap, Wc1, bc1, Wc2, bc2, fusedT);
    gemm_out_mfma<<<dim3(8, 16, 4), 256, 0, stream>>>(Wob, fusedT, bo, x, out);
}

// Round 8
// 279.748 us; speedup vs baseline: 1.4418x; 1.3350x over previous
//
#include <hip/hip_runtime.h>
#include <hip/hip_fp8.h>
#include <stdint.h>

typedef unsigned short u16;
typedef unsigned char u8;
typedef __attribute__((ext_vector_type(8))) __bf16 bf16x8;
typedef __attribute__((ext_vector_type(8))) short short8s;
typedef __attribute__((ext_vector_type(4))) float float4v;
typedef __attribute__((ext_vector_type(16))) float floatx16;

// ---------- sizes ----------
static constexpr int NB = 4, NC = 256, NH = 64, NW = 64, NHW = 4096;
static constexpr int BC = 32;        // kv tile
static constexpr int NKV = 4;        // kv split factor
static constexpr int KVCHUNK = NHW / NKV;   // 1024

// ---------- workspace layout (lifetime-aliased) ----------
static constexpr size_t MB = 1ull << 20;
static constexpr size_t OFF_KBF    = 0;          // bf16 [B][C][N] 8MB (dead after transpose)
static constexpr size_t OFF_LBF    = 8 * MB;     // bf16 [B][C][N] 8MB (dead after transpose)
static constexpr size_t OFF_GT     = 0;          // bf16 [B][N][C] 8MB — overlays KBF
static constexpr size_t OFF_XT     = 16 * MB;    // bf16 [B][N][C] 8MB (dead after gemm_qhid)
static constexpr size_t OFF_FUSEDT = 16 * MB;    // bf16 [B][N][C] 8MB — overlays XT
static constexpr size_t OFF_QT8    = 24 * MB;    // fp8 [B][N][C] 4MB
static constexpr size_t OFF_KT8    = 32 * MB;    // fp8 [B][N][C] 4MB
static constexpr size_t OFF_VBF    = 40 * MB;    // bf16 [B][C][N] 8MB
static constexpr size_t OFF_LT     = 48 * MB;    // bf16 [B][N][C] 8MB (localT)
static constexpr size_t OFF_OPART  = 56 * MB;    // bf16 [B][NKV][N][C] 32MB
static constexpr size_t OFF_LPART  = 88 * MB;    // fp32 [B][NKV][N] 256KB
static constexpr size_t OFF_HIDT   = OFF_LPART + 256 * 1024;   // bf16 [B][N][64] 2MB
static constexpr size_t OFF_GAP    = OFF_HIDT + 2 * MB;        // fp32 [B][256]
static constexpr size_t OFF_WQB    = OFF_GAP + 8 * 1024;       // bf16 256x256
static constexpr size_t OFF_WS1B   = OFF_WQB + 131072;         // bf16 64x256
static constexpr size_t OFF_WS2B   = OFF_WS1B + 32768;         // bf16 256x64
static constexpr size_t OFF_WOB    = OFF_WS2B + 32768;         // bf16 256x256

__device__ __forceinline__ float b2f(u16 h) {
    union { float f; unsigned u; } v; v.u = ((unsigned)h) << 16; return v.f;
}
__device__ __forceinline__ u16 f2b(float f) {
    union { float f; unsigned u; } v; v.f = f;
    unsigned r = v.u + 0x7fffu + ((v.u >> 16) & 1u);
    return (u16)(r >> 16);
}
__device__ __forceinline__ u8 f2f8(float f) {
    __hip_fp8_e4m3 h(f);
    return *reinterpret_cast<u8*>(&h);
}

// async global->LDS, 16B per lane; ldst wave-uniform (HW adds lane*16)
__device__ __forceinline__ void load_lds16(const void* gsrc, void* ldst) {
    __builtin_amdgcn_global_load_lds(
        (__attribute__((address_space(1))) void*)(uintptr_t)gsrc,
        (__attribute__((address_space(3))) void*)ldst,
        16, 0, 0);
}

// ---------- prep mega-kernel: weights+gap | dw k/v/local (register pipeline) | x transpose ----------
// zone A: [0,644) weights fp32->bf16 + gap zero
// zone B: [644,2692) depthwise k,v,local — x/v rows in registers, col-neighbors via shuffle
// zone C: [2692,3716) x fp32 [C][N] -> bf16 [N][C]
__global__ __launch_bounds__(256) void prep(
    const float* __restrict__ x,
    const float* __restrict__ Wq, const float* __restrict__ Ws1,
    const float* __restrict__ Ws2, const float* __restrict__ Wo,
    const float* __restrict__ Wk, const float* __restrict__ bk,
    const float* __restrict__ Wv, const float* __restrict__ bv,
    const float* __restrict__ Wl, const float* __restrict__ bl,
    u16* __restrict__ Wqb, u16* __restrict__ Ws1b, u16* __restrict__ Ws2b, u16* __restrict__ Wob,
    float* __restrict__ gap,
    u16* __restrict__ k_bf, u16* __restrict__ vN, u16* __restrict__ local_bf,
    u16* __restrict__ xT)
{
    __shared__ __align__(16) unsigned char pshm[9216];
    const int bid = blockIdx.x;
    const int t = threadIdx.x;

    if (bid < 644) {
        int id = bid * 256 + t;
        if (id < 65536)        Wqb[id] = f2b(Wq[id]);
        else if (id < 81920)   Ws1b[id - 65536] = f2b(Ws1[id - 65536]);
        else if (id < 98304)   Ws2b[id - 81920] = f2b(Ws2[id - 81920]);
        else if (id < 163840)  Wob[id - 98304] = f2b(Wo[id - 98304]);
        else if (id < 164864)  gap[id - 163840] = 0.f;
        return;
    }
    if (bid < 2692) {
        // ---- depthwise k, v, local: fully register-resident row pipeline ----
        int l = bid - 644;
        int xx0 = t & 63, cl = t >> 6;        // one wave per channel; lane == xx0
        int y0 = (l & 7) * 8;
        int c  = ((l >> 3) & 63) * 4 + cl;
        int b  = l >> 9;
        const float* xb = x + ((size_t)b * NC + c) * NHW;
        float wk[9], wv[9], wl[9];
#pragma unroll
        for (int i = 0; i < 9; i++) { wk[i] = Wk[c*9+i]; wv[i] = Wv[c*9+i]; wl[i] = Wl[c*9+i]; }
        float bkc = bk[c], bvc = bv[c], blc = bl[c];

        auto ldx = [&](int y) -> float {
            return ((unsigned)y <= 63u) ? xb[y * 64 + xx0] : 0.f;
        };
        auto conv3 = [&](const float* w9, float a, float bm, float cc) -> float {
            float au = __shfl_up(a, 1, 64),   ad = __shfl_down(a, 1, 64);
            float bu = __shfl_up(bm, 1, 64),  bd = __shfl_down(bm, 1, 64);
            float cu = __shfl_up(cc, 1, 64),  cd = __shfl_down(cc, 1, 64);
            float al = (xx0 == 0) ? 0.f : au, ar = (xx0 == 63) ? 0.f : ad;
            float bl_ = (xx0 == 0) ? 0.f : bu, br = (xx0 == 63) ? 0.f : bd;
            float cle = (xx0 == 0) ? 0.f : cu, cr = (xx0 == 63) ? 0.f : cd;
            return w9[0]*al + w9[1]*a  + w9[2]*ar
                 + w9[3]*bl_ + w9[4]*bm + w9[5]*br
                 + w9[6]*cle + w9[7]*cc + w9[8]*cr;
        };

        float xm2 = ldx(y0 - 2), xm1 = ldx(y0 - 1), x0v = ldx(y0), xp1 = ldx(y0 + 1);
        float vm1 = (y0 - 1 >= 0) ? (bvc + conv3(wv, xm2, xm1, x0v)) : 0.f;
        float v0  = bvc + conv3(wv, xm1, x0v, xp1);

        size_t base = ((size_t)b * NC + c) * NHW;
#pragma unroll
        for (int yi = 0; yi < 8; yi++) {
            int y = y0 + yi;
            float xp2 = ldx(y + 2);
            float vp1 = (y + 1 <= 63) ? (bvc + conv3(wv, x0v, xp1, xp2)) : 0.f;
            float kk  = bkc + conv3(wk, xm1, x0v, xp1);
            float ll  = blc + conv3(wl, vm1, v0, vp1);
            size_t o = base + y * 64 + xx0;
            k_bf[o]     = f2b(kk);
            vN[o]       = f2b(v0);
            local_bf[o] = f2b(ll);
            xm1 = x0v; x0v = xp1; xp1 = xp2;
            vm1 = v0;  v0 = vp1;
        }
        return;
    }
    {
        // ---- transpose-convert x ----
        u16 (*tile)[72] = reinterpret_cast<u16 (*)[72]>(pshm);
        int l = bid - 2692;
        int n0 = (l & 63) * 64;
        int c0 = ((l >> 6) & 3) * 64;
        int b  = l >> 8;
        const float* src = x + (size_t)b * NC * NHW;
        u16* dst = xT + (size_t)b * NHW * NC;
        int c = t >> 2, nb = (t & 3) * 16;
#pragma unroll
        for (int q = 0; q < 4; q++) {
            float4 v = *(const float4*)(src + (size_t)(c0 + c) * NHW + n0 + nb + q * 4);
            tile[c][nb + q * 4 + 0] = f2b(v.x);
            tile[c][nb + q * 4 + 1] = f2b(v.y);
            tile[c][nb + q * 4 + 2] = f2b(v.z);
            tile[c][nb + q * 4 + 3] = f2b(v.w);
        }
        __syncthreads();
        int cl = t & 63, ng = t >> 6;
#pragma unroll
        for (int j = 0; j < 16; j++) {
            int n = ng * 16 + j;
            dst[(size_t)(n0 + n) * NC + c0 + cl] = tile[cl][n];
        }
    }
}

// ---------- bf16 transpose [C][N] -> [N][C]: k -> fp8 kT8, local -> bf16 localT ----------
__global__ __launch_bounds__(256) void transpose_bf(
    const u16* __restrict__ k_bf, const u16* __restrict__ local_bf,
    u8* __restrict__ kT8, u16* __restrict__ localT)
{
    __shared__ u16 tile[64][72];
    int n0 = blockIdx.x * 64, c0 = blockIdx.y * 64;
    int zb = blockIdx.z, b = zb >> 1;
    const u16* src = (zb & 1) ? local_bf : k_bf;
    src += (size_t)b * NC * NHW;
    int t = threadIdx.x;
    int c = t >> 2, nb = (t & 3) * 16;
    *(short8s*)&tile[c][nb]     = *(const short8s*)(src + (size_t)(c0 + c) * NHW + n0 + nb);
    *(short8s*)&tile[c][nb + 8] = *(const short8s*)(src + (size_t)(c0 + c) * NHW + n0 + nb + 8);
    __syncthreads();
    int cl = t & 63, ng = t >> 6;
    if (zb & 1) {
        u16* dst = localT + (size_t)b * NHW * NC;
#pragma unroll
        for (int j = 0; j < 16; j++) {
            int n = ng * 16 + j;
            dst[(size_t)(n0 + n) * NC + c0 + cl] = tile[cl][n];
        }
    } else {
        u8* dst = kT8 + (size_t)b * NHW * NC;
#pragma unroll
        for (int j = 0; j < 16; j++) {
            int n = ng * 16 + j;
            dst[(size_t)(n0 + n) * NC + c0 + cl] = f2f8(b2f(tile[cl][n]));
        }
    }
}

// ---------- fused MFMA GEMMs: qT8 = fp8(xT.Wq^T + bq)  |  hidT = relu(localT.Ws1^T + bs1) ----------
__global__ __launch_bounds__(256) void gemm_qhid(
    const u16* __restrict__ xT, const u16* __restrict__ Wqb, const float* __restrict__ bq,
    u8* __restrict__ qT8,
    const u16* __restrict__ localT, const u16* __restrict__ Ws1b, const float* __restrict__ bs1,
    u16* __restrict__ hidT)
{
    const int t = threadIdx.x, w = t >> 6, lane = t & 63;
    const int lm = lane & 15, quad = lane >> 4;
    const int zone = blockIdx.x >> 9;           // 0: q, 1: hid
    const int l = blockIdx.x & 511;
    const int b = l >> 7;
    const int s_base = (l & 127) * 32 + (w & 1) * 16;

    if (zone == 0) {
        const int ch = (w >> 1) * 128;
        const u16* xTb = xT + (size_t)b * NHW * NC;
        u8* qTb = qT8 + (size_t)b * NHW * NC;
        bf16x8 aq[8];
#pragma unroll
        for (int kt = 0; kt < 8; kt++)
            aq[kt] = *(const bf16x8*)(xTb + (size_t)(s_base + lm) * NC + kt * 32 + quad * 8);
        float4v acc[8];
#pragma unroll
        for (int j = 0; j < 8; j++) acc[j] = (float4v){0.f, 0.f, 0.f, 0.f};
#pragma unroll
        for (int kt = 0; kt < 8; kt++) {
#pragma unroll
            for (int j = 0; j < 8; j++) {
                bf16x8 bw = *(const bf16x8*)(Wqb + (size_t)(ch + j * 16 + lm) * 256 + kt * 32 + quad * 8);
                acc[j] = __builtin_amdgcn_mfma_f32_16x16x32_bf16(aq[kt], bw, acc[j], 0, 0, 0);
            }
        }
#pragma unroll
        for (int j = 0; j < 8; j++) {
            int cout = ch + j * 16 + lm;
            float bb = bq[cout];
#pragma unroll
            for (int r = 0; r < 4; r++) {
                int s = s_base + quad * 4 + r;
                qTb[(size_t)s * NC + cout] = f2f8(acc[j][r] + bb);
            }
        }
    } else {
        const int ch = (w >> 1) * 32;
        const u16* lTb = localT + (size_t)b * NHW * NC;
        u16* hTb = hidT + (size_t)b * NHW * 64;
        bf16x8 aq[8];
#pragma unroll
        for (int kt = 0; kt < 8; kt++)
            aq[kt] = *(const bf16x8*)(lTb + (size_t)(s_base + lm) * NC + kt * 32 + quad * 8);
        float4v acc[2];
#pragma unroll
        for (int j = 0; j < 2; j++) acc[j] = (float4v){0.f, 0.f, 0.f, 0.f};
#pragma unroll
        for (int kt = 0; kt < 8; kt++) {
#pragma unroll
            for (int j = 0; j < 2; j++) {
                bf16x8 bw = *(const bf16x8*)(Ws1b + (size_t)(ch + j * 16 + lm) * 256 + kt * 32 + quad * 8);
                acc[j] = __builtin_amdgcn_mfma_f32_16x16x32_bf16(aq[kt], bw, acc[j], 0, 0, 0);
            }
        }
#pragma unroll
        for (int j = 0; j < 2; j++) {
            int h = ch + j * 16 + lm;
            float bb = bs1[h];
#pragma unroll
            for (int r = 0; r < 4; r++) {
                int s = s_base + quad * 4 + r;
                hTb[(size_t)s * 64 + h] = f2b(fmaxf(acc[j][r] + bb, 0.0f));
            }
        }
    }
}

// ---------- staging: K fp8 tile (2 DMA/wave) + V bf16 tile (4 DMA/wave) ----------
__device__ __forceinline__ void stage_tiles(
    const u8* __restrict__ kb, const u16* __restrict__ vNb, int kv0,
    u8* KlB, u16* VlB, int w, int lane)
{
#pragma unroll
    for (int i = 0; i < 2; i++) {
        int g = (w * 2 + i) * 64 + lane;
        int n = g >> 4, jj = g & 15, cc = jj ^ (n & 15);
        load_lds16(kb + (size_t)(kv0 + n) * NC + cc * 16, KlB + (w * 2 + i) * 1024);
    }
#pragma unroll
    for (int i = 0; i < 4; i++) {
        int g = (w * 4 + i) * 64 + lane;
        int c = g >> 2, jj = g & 3, ck = (jj - (c >> 1)) & 3;
        load_lds16(vNb + (size_t)c * NHW + kv0 + ck * 8, (char*)VlB + (w * 4 + i) * 1024);
    }
}

// ---------- flash attention: fp8 QK (32x32x16_fp8), bf16 PV; S^T + half-wave P shuffle ----------
// grid 512: combo=(b*4+jc)=blockIdx&15 (XCD-local), qt=blockIdx>>4 -> 128-row q block.
// aq fp8 = 32 VGPRs (was 64 bf16) -> total regs ~240, no spill (checkpoint: WRITE_SIZE ~34MB).
__global__ __launch_bounds__(256, 2) void attn_split(
    const u8* __restrict__ qT8, const u8* __restrict__ kT8,
    const u16* __restrict__ vN, u16* __restrict__ Opart, float* __restrict__ lpart)
{
    __shared__ __align__(16) u8 Kl[2][BC * 256];    // 2 x 8KB fp8
    __shared__ __align__(16) u16 Vl[2][256 * BC];   // 2 x 16KB bf16

    const int combo = blockIdx.x & 15;
    const int b  = combo >> 2;
    const int jc = combo & 3;
    const int n0 = (blockIdx.x >> 4) * 128;
    const int t = threadIdx.x;
    const int w = t >> 6, lane = t & 63;
    const int lr = lane & 31, l5 = lane >> 5;

    const u8* qb = qT8 + (size_t)b * NHW * NC;
    const u8* kb = kT8 + (size_t)b * NHW * NC;
    const u16* vNb = vN + (size_t)b * NC * NHW;

    // Q frags (B-operand of S^T): B[k=ch][n=q=lr], 8 fp8/lane per frag (2 VGPRs)
    long aq[16];
    {
        int qrow = n0 + w * 32 + lr;
#pragma unroll
        for (int kt = 0; kt < 16; kt++)
            aq[kt] = *(const long*)(qb + (size_t)qrow * NC + kt * 16 + l5 * 8);
    }

    floatx16 oacc[8];
#pragma unroll
    for (int i = 0; i < 8; i++)
#pragma unroll
        for (int j = 0; j < 16; j++) oacc[i][j] = 0.f;
    float lsum = 0.f;

    const int kvbeg = jc * KVCHUNK;
    stage_tiles(kb, vNb, kvbeg, Kl[0], Vl[0], w, lane);

    int buf = 0;
#pragma unroll 1
    for (int it = 0; it < KVCHUNK / BC; it++) {
        const int kv0 = kvbeg + it * BC;
        const int nxt = (it + 1 < KVCHUNK / BC) ? (kv0 + BC) : kvbeg;
        stage_tiles(kb, vNb, nxt, Kl[buf ^ 1], Vl[buf ^ 1], w, lane);
        asm volatile("s_waitcnt vmcnt(6)" ::: "memory");
        __builtin_amdgcn_s_barrier();

        const u8* KlB = Kl[buf];
        const u16* VlB = Vl[buf];

        // S^T[kv][q]: A = K fp8 [m=kv=lr][k=ch], B = Q fp8 regs
        floatx16 sacc;
#pragma unroll
        for (int j = 0; j < 16; j++) sacc[j] = 0.f;
#pragma unroll
        for (int kt = 0; kt < 16; kt++) {
            long ak = *(const long*)&KlB[lr * 256 + ((kt ^ (lr & 15)) * 16) + l5 * 8];
            sacc = __builtin_amdgcn_mfma_f32_32x32x16_fp8_fp8(ak, aq[kt], sacc, 0, 0, 0);
        }
        // exp + per-q row sum (q = lane dim) + pack bf16 pairs
        unsigned pk[8];
#pragma unroll
        for (int g2 = 0; g2 < 8; g2++) {
            float p0 = __expf(sacc[g2 * 2 + 0] * 0.0625f);
            float p1 = __expf(sacc[g2 * 2 + 1] * 0.0625f);
            lsum += p0 + p1;
            union { float f; unsigned u; } a, bb;
            a.f = p0; bb.f = p1;
            pk[g2] = (bb.u & 0xffff0000u) | (a.u >> 16);   // truncate; bias cancels in O/l
        }
        // half-wave exchange -> P A-frags (bf16): A[m=q=lr][k=kv]
        unsigned rA = (unsigned)__shfl_xor((int)(l5 ? pk[0] : pk[2]), 32, 64);
        unsigned rB = (unsigned)__shfl_xor((int)(l5 ? pk[1] : pk[3]), 32, 64);
        unsigned rC = (unsigned)__shfl_xor((int)(l5 ? pk[4] : pk[6]), 32, 64);
        unsigned rD = (unsigned)__shfl_xor((int)(l5 ? pk[5] : pk[7]), 32, 64);
        union { unsigned u[4]; bf16x8 v; } f0, f1;
        f0.u[0] = l5 ? rA : pk[0];  f0.u[1] = l5 ? rB : pk[1];
        f0.u[2] = l5 ? pk[2] : rA;  f0.u[3] = l5 ? pk[3] : rB;
        f1.u[0] = l5 ? rC : pk[4];  f1.u[1] = l5 ? rD : pk[5];
        f1.u[2] = l5 ? pk[6] : rC;  f1.u[3] = l5 ? pk[7] : rD;

        // PV (bf16): O += P @ V
#pragma unroll
        for (int ct = 0; ct < 8; ct++) {
            int c = ct * 32 + lr;
            int vb = c * 32;
            bf16x8 bv0 = *(const bf16x8*)&VlB[vb + (((l5 + (c >> 1)) & 3)) * 8];
            bf16x8 bv1 = *(const bf16x8*)&VlB[vb + (((2 + l5 + (c >> 1)) & 3)) * 8];
            oacc[ct] = __builtin_amdgcn_mfma_f32_32x32x16_bf16(f0.v, bv0, oacc[ct], 0, 0, 0);
            oacc[ct] = __builtin_amdgcn_mfma_f32_32x32x16_bf16(f1.v, bv1, oacc[ct], 0, 0, 0);
        }
        __builtin_amdgcn_s_barrier();
        buf ^= 1;
    }

    // epilogue: unnormalized partial O (bf16) + partial l
    lsum += __shfl_xor(lsum, 32, 64);
    u16* Ob = Opart + ((size_t)(b * NKV + jc) * NHW + n0 + w * 32) * NC;
#pragma unroll
    for (int reg = 0; reg < 16; reg++) {
        int row = (reg & 3) + 8 * (reg >> 2) + 4 * l5;
#pragma unroll
        for (int ct = 0; ct < 8; ct++)
            Ob[(size_t)row * NC + ct * 32 + lr] = f2b(oacc[ct][reg]);
    }
    if (lane < 32)
        lpart[(size_t)(b * NKV + jc) * NHW + n0 + w * 32 + lr] = lsum;
}

// ---------- combine kv-split partials (gT bf16) + fused gap reduce ----------
__global__ __launch_bounds__(256) void attn_combine(
    const u16* __restrict__ Opart, const float* __restrict__ lpart,
    u16* __restrict__ gT, float* __restrict__ gap)
{
    __shared__ float gsum[256];
    int t = threadIdx.x;
    gsum[t] = 0.f;
    __syncthreads();
    int b = blockIdx.y;
    int n = blockIdx.x * 8 + (t >> 5);
    int c0 = (t & 31) * 8;
    float acc[8] = {};
    float l = 0.f;
#pragma unroll
    for (int j = 0; j < NKV; j++) {
        const u16* op = Opart + ((size_t)(b * NKV + j) * NHW + n) * NC + c0;
        short8s v = *(const short8s*)op;
#pragma unroll
        for (int i = 0; i < 8; i++) acc[i] += b2f(((const u16*)&v)[i]);
        l += lpart[(size_t)(b * NKV + j) * NHW + n];
    }
    float inv = 1.0f / l;
#pragma unroll
    for (int i = 0; i < 8; i++) acc[i] *= inv;
    short8s vo;
#pragma unroll
    for (int i = 0; i < 8; i++) ((u16*)&vo)[i] = f2b(acc[i]);
    *(short8s*)(gT + ((size_t)b * NHW + n) * NC + c0) = vo;
#pragma unroll
    for (int i = 0; i < 8; i++) atomicAdd(&gsum[c0 + i], acc[i]);
    __syncthreads();
    atomicAdd(&gap[b * NC + t], gsum[t]);
}

// ---------- MFMA GEMM + inline channel-MLP + fuse ----------
__global__ __launch_bounds__(256) void gemm_swfused_mfma(
    const u16* __restrict__ hidT, const u16* __restrict__ Ws2b, const float* __restrict__ bs2,
    const u16* __restrict__ gT, const u16* __restrict__ localT,
    const float* __restrict__ gap,
    const float* __restrict__ Wc1, const float* __restrict__ bc1,
    const float* __restrict__ Wc2, const float* __restrict__ bc2,
    u16* __restrict__ fusedT)
{
    __shared__ float g[256], h1[32], cwl[256];
    __shared__ float ph[32][9];
    const int t = threadIdx.x, w = t >> 6, lane = t & 63;
    const int lm = lane & 15, quad = lane >> 4;
    const int b = blockIdx.y;

    g[t] = gap[b * 256 + t] * (1.0f / 4096.0f);
    __syncthreads();
    {
        int h = t & 31, part = t >> 5;
        float s = 0.f;
        for (int c = part * 32; c < part * 32 + 32; c++) s += Wc1[h * 256 + c] * g[c];
        ph[h][part] = s;
    }
    __syncthreads();
    if (t < 32) {
        float s = bc1[t];
#pragma unroll
        for (int p = 0; p < 8; p++) s += ph[t][p];
        h1[t] = fmaxf(s, 0.f);
    }
    __syncthreads();
    {
        float s = bc2[t];
#pragma unroll
        for (int j = 0; j < 32; j++) s += Wc2[t * 32 + j] * h1[j];
        cwl[t] = 1.0f / (1.0f + __expf(-s));
    }
    __syncthreads();

    const int s_base = blockIdx.x * 32 + (w & 1) * 16;
    const int ch = (w >> 1) * 128;
    const u16* hTb = hidT + (size_t)b * NHW * 64;
    const u16* lTb = localT + (size_t)b * NHW * NC;
    const u16* gTb = gT + (size_t)b * NHW * NC;
    u16* fTb = fusedT + (size_t)b * NHW * NC;

    bf16x8 aq[2];
#pragma unroll
    for (int kt = 0; kt < 2; kt++)
        aq[kt] = *(const bf16x8*)(hTb + (size_t)(s_base + lm) * 64 + kt * 32 + quad * 8);

    float4v acc[8];
#pragma unroll
    for (int j = 0; j < 8; j++) acc[j] = (float4v){0.f, 0.f, 0.f, 0.f};

#pragma unroll
    for (int kt = 0; kt < 2; kt++) {
#pragma unroll
        for (int j = 0; j < 8; j++) {
            bf16x8 bw = *(const bf16x8*)(Ws2b + (size_t)(ch + j * 16 + lm) * 64 + kt * 32 + quad * 8);
            acc[j] = __builtin_amdgcn_mfma_f32_16x16x32_bf16(aq[kt], bw, acc[j], 0, 0, 0);
        }
    }
#pragma unroll
    for (int j = 0; j < 8; j++) {
        int c = ch + j * 16 + lm;
        float bb = bs2[c];
        float cwv = cwl[c];
#pragma unroll
        for (int r = 0; r < 4; r++) {
            int s = s_base + quad * 4 + r;
            float sw = 1.0f / (1.0f + __expf(-(acc[j][r] + bb)));
            float gg = b2f(gTb[(size_t)s * NC + c]);
            float lo = b2f(lTb[(size_t)s * NC + c]);
            fTb[(size_t)s * NC + c] = f2b(gg * cwv + lo * sw);
        }
    }
}

// ---------- MFMA GEMM: out[o][n] = Wo[o][:] . fusedT[n][:] + bo + x ----------
__global__ __launch_bounds__(256) void gemm_out_mfma(
    const u16* __restrict__ Wob, const u16* __restrict__ fusedT, const float* __restrict__ bo,
    const float* __restrict__ x, float* __restrict__ out)
{
    const int t = threadIdx.x, w = t >> 6, lane = t & 63;
    const int lm = lane & 15, quad = lane >> 4;
    const int b = blockIdx.z;
    const int o_base = blockIdx.x * 32 + (w & 1) * 16;
    const int n_base = blockIdx.y * 256 + (w >> 1) * 128;
    const u16* fTb = fusedT + (size_t)b * NHW * NC;

    bf16x8 aw[8];
#pragma unroll
    for (int kt = 0; kt < 8; kt++)
        aw[kt] = *(const bf16x8*)(Wob + (size_t)(o_base + lm) * 256 + kt * 32 + quad * 8);

    float4v acc[8];
#pragma unroll
    for (int j = 0; j < 8; j++) acc[j] = (float4v){0.f, 0.f, 0.f, 0.f};

#pragma unroll
    for (int kt = 0; kt < 8; kt++) {
#pragma unroll
        for (int j = 0; j < 8; j++) {
            bf16x8 bf = *(const bf16x8*)(fTb + (size_t)(n_base + j * 16 + lm) * NC + kt * 32 + quad * 8);
            acc[j] = __builtin_amdgcn_mfma_f32_16x16x32_bf16(aw[kt], bf, acc[j], 0, 0, 0);
        }
    }
#pragma unroll
    for (int r = 0; r < 4; r++) {
        int o = o_base + quad * 4 + r;
        float bb = bo[o];
        size_t rowoff = ((size_t)b * NC + o) * NHW;
#pragma unroll
        for (int j = 0; j < 8; j++) {
            int n = n_base + j * 16 + lm;
            out[rowoff + n] = acc[j][r] + bb + x[rowoff + n];
        }
    }
}

extern "C" void kernel_launch(void* const* d_in, const int* in_sizes, int n_in,
                              void* d_out, int out_size, void* d_ws, size_t ws_size,
                              hipStream_t stream)
{
    const float* x   = (const float*)d_in[0];
    const float* Wq  = (const float*)d_in[1];
    const float* bq  = (const float*)d_in[2];
    const float* Wk  = (const float*)d_in[3];
    const float* bk  = (const float*)d_in[4];
    const float* Wv  = (const float*)d_in[5];
    const float* bv  = (const float*)d_in[6];
    const float* Wl  = (const float*)d_in[7];
    const float* bl  = (const float*)d_in[8];
    const float* Ws1 = (const float*)d_in[9];
    const float* bs1 = (const float*)d_in[10];
    const float* Ws2 = (const float*)d_in[11];
    const float* bs2 = (const float*)d_in[12];
    const float* Wc1 = (const float*)d_in[13];
    const float* bc1 = (const float*)d_in[14];
    const float* Wc2 = (const float*)d_in[15];
    const float* bc2 = (const float*)d_in[16];
    const float* Wo  = (const float*)d_in[17];
    const float* bo  = (const float*)d_in[18];
    float* out = (float*)d_out;

    char* ws = (char*)d_ws;
    u16* k_bf     = (u16*)(ws + OFF_KBF);
    u16* local_bf = (u16*)(ws + OFF_LBF);
    u16* gT       = (u16*)(ws + OFF_GT);
    u16* xT       = (u16*)(ws + OFF_XT);
    u16* fusedT   = (u16*)(ws + OFF_FUSEDT);
    u8*  qT8      = (u8*)(ws + OFF_QT8);
    u8*  kT8      = (u8*)(ws + OFF_KT8);
    u16* vN       = (u16*)(ws + OFF_VBF);
    u16* localT   = (u16*)(ws + OFF_LT);
    u16* Opart    = (u16*)(ws + OFF_OPART);
    float* lpart  = (float*)(ws + OFF_LPART);
    u16* hidT     = (u16*)(ws + OFF_HIDT);
    float* gap    = (float*)(ws + OFF_GAP);
    u16* Wqb      = (u16*)(ws + OFF_WQB);
    u16* Ws1b     = (u16*)(ws + OFF_WS1B);
    u16* Ws2b     = (u16*)(ws + OFF_WS2B);
    u16* Wob      = (u16*)(ws + OFF_WOB);

    prep<<<dim3(3716), 256, 0, stream>>>(x, Wq, Ws1, Ws2, Wo, Wk, bk, Wv, bv, Wl, bl,
                                         Wqb, Ws1b, Ws2b, Wob, gap, k_bf, vN, local_bf, xT);
    transpose_bf<<<dim3(64, 4, 8), 256, 0, stream>>>(k_bf, local_bf, kT8, localT);
    gemm_qhid<<<dim3(1024), 256, 0, stream>>>(xT, Wqb, bq, qT8, localT, Ws1b, bs1, hidT);
    attn_split<<<dim3(512), 256, 0, stream>>>(qT8, kT8, vN, Opart, lpart);
    attn_combine<<<dim3(NHW / 8, 4), 256, 0, stream>>>(Opart, lpart, gT, gap);
    gemm_swfused_mfma<<<dim3(128, 4), 256, 0, stream>>>(hidT, Ws2b, bs2, gT, localT,
                                                        gap, Wc1, bc1, Wc2, bc2, fusedT);
    gemm_out_mfma<<<dim3(8, 16, 4), 256, 0, stream>>>(Wob, fusedT, bo, x, out);
}

// Round 9
// 279.119 us; speedup vs baseline: 1.4450x; 1.0023x over previous
//
#include <hip/hip_runtime.h>
#include <hip/hip_fp8.h>
#include <stdint.h>

typedef unsigned short u16;
typedef unsigned char u8;
typedef __attribute__((ext_vector_type(8))) __bf16 bf16x8;
typedef __attribute__((ext_vector_type(8))) short short8s;
typedef __attribute__((ext_vector_type(4))) float float4v;
typedef __attribute__((ext_vector_type(16))) float floatx16;

// ---------- sizes ----------
static constexpr int NB = 4, NC = 256, NH = 64, NW = 64, NHW = 4096;
static constexpr int BC = 32;        // kv tile
static constexpr int NKV = 4;        // kv split factor
static constexpr int KVCHUNK = NHW / NKV;   // 1024

// ---------- workspace layout (lifetime-aliased) ----------
static constexpr size_t MB = 1ull << 20;
static constexpr size_t OFF_KBF    = 0;          // bf16 [B][C][N] 8MB (dead after mid)
static constexpr size_t OFF_LBF    = 8 * MB;     // bf16 [B][C][N] 8MB (dead after mid)
static constexpr size_t OFF_GT     = 0;          // bf16 [B][N][C] 8MB — overlays KBF
static constexpr size_t OFF_XT     = 16 * MB;    // bf16 [B][N][C] 8MB (dead after mid)
static constexpr size_t OFF_FUSEDT = 16 * MB;    // bf16 [B][N][C] 8MB — overlays XT
static constexpr size_t OFF_QT8    = 24 * MB;    // fp8 [B][N][C] 4MB
static constexpr size_t OFF_KT8    = 32 * MB;    // fp8 [B][N][C] 4MB
static constexpr size_t OFF_V8     = 40 * MB;    // fp8 [B][C][N] 4MB
static constexpr size_t OFF_LT     = 48 * MB;    // bf16 [B][N][C] 8MB (localT)
static constexpr size_t OFF_OPART  = 56 * MB;    // fp8 [B][NKV][N][C] 16MB
static constexpr size_t OFF_LPART  = 88 * MB;    // fp32 [B][NKV][N] 256KB
static constexpr size_t OFF_HIDT   = OFF_LPART + 256 * 1024;   // bf16 [B][N][64] 2MB
static constexpr size_t OFF_GAP    = OFF_HIDT + 2 * MB;        // fp32 [B][256]
static constexpr size_t OFF_WQB    = OFF_GAP + 8 * 1024;       // bf16 256x256
static constexpr size_t OFF_WS1B   = OFF_WQB + 131072;         // bf16 64x256
static constexpr size_t OFF_WS2B   = OFF_WS1B + 32768;         // bf16 256x64
static constexpr size_t OFF_WOB    = OFF_WS2B + 32768;         // bf16 256x256

__device__ __forceinline__ float b2f(u16 h) {
    union { float f; unsigned u; } v; v.u = ((unsigned)h) << 16; return v.f;
}
__device__ __forceinline__ u16 f2b(float f) {
    union { float f; unsigned u; } v; v.f = f;
    unsigned r = v.u + 0x7fffu + ((v.u >> 16) & 1u);
    return (u16)(r >> 16);
}
__device__ __forceinline__ u8 f2f8(float f) {
    __hip_fp8_e4m3 h(f);
    return *reinterpret_cast<u8*>(&h);
}

// async global->LDS, 16B per lane; ldst wave-uniform (HW adds lane*16)
__device__ __forceinline__ void load_lds16(const void* gsrc, void* ldst) {
    __builtin_amdgcn_global_load_lds(
        (__attribute__((address_space(1))) void*)(uintptr_t)gsrc,
        (__attribute__((address_space(3))) void*)ldst,
        16, 0, 0);
}

// ---------- prep mega-kernel: weights+gap | dw k/v(fp8)/local | x transpose ----------
__global__ __launch_bounds__(256) void prep(
    const float* __restrict__ x,
    const float* __restrict__ Wq, const float* __restrict__ Ws1,
    const float* __restrict__ Ws2, const float* __restrict__ Wo,
    const float* __restrict__ Wk, const float* __restrict__ bk,
    const float* __restrict__ Wv, const float* __restrict__ bv,
    const float* __restrict__ Wl, const float* __restrict__ bl,
    u16* __restrict__ Wqb, u16* __restrict__ Ws1b, u16* __restrict__ Ws2b, u16* __restrict__ Wob,
    float* __restrict__ gap,
    u16* __restrict__ k_bf, u8* __restrict__ vN8, u16* __restrict__ local_bf,
    u16* __restrict__ xT)
{
    __shared__ __align__(16) unsigned char pshm[9216];
    const int bid = blockIdx.x;
    const int t = threadIdx.x;

    if (bid < 644) {
        int id = bid * 256 + t;
        if (id < 65536)        Wqb[id] = f2b(Wq[id]);
        else if (id < 81920)   Ws1b[id - 65536] = f2b(Ws1[id - 65536]);
        else if (id < 98304)   Ws2b[id - 81920] = f2b(Ws2[id - 81920]);
        else if (id < 163840)  Wob[id - 98304] = f2b(Wo[id - 98304]);
        else if (id < 164864)  gap[id - 163840] = 0.f;
        return;
    }
    if (bid < 2692) {
        // ---- depthwise k, v, local: register row pipeline, col-neighbors via shuffle ----
        int l = bid - 644;
        int xx0 = t & 63, cl = t >> 6;
        int y0 = (l & 7) * 8;
        int c  = ((l >> 3) & 63) * 4 + cl;
        int b  = l >> 9;
        const float* xb = x + ((size_t)b * NC + c) * NHW;
        float wk[9], wv[9], wl[9];
#pragma unroll
        for (int i = 0; i < 9; i++) { wk[i] = Wk[c*9+i]; wv[i] = Wv[c*9+i]; wl[i] = Wl[c*9+i]; }
        float bkc = bk[c], bvc = bv[c], blc = bl[c];

        auto ldx = [&](int y) -> float {
            return ((unsigned)y <= 63u) ? xb[y * 64 + xx0] : 0.f;
        };
        auto conv3 = [&](const float* w9, float a, float bm, float cc) -> float {
            float au = __shfl_up(a, 1, 64),   ad = __shfl_down(a, 1, 64);
            float bu = __shfl_up(bm, 1, 64),  bd = __shfl_down(bm, 1, 64);
            float cu = __shfl_up(cc, 1, 64),  cd = __shfl_down(cc, 1, 64);
            float al = (xx0 == 0) ? 0.f : au, ar = (xx0 == 63) ? 0.f : ad;
            float bl_ = (xx0 == 0) ? 0.f : bu, br = (xx0 == 63) ? 0.f : bd;
            float cle = (xx0 == 0) ? 0.f : cu, cr = (xx0 == 63) ? 0.f : cd;
            return w9[0]*al + w9[1]*a  + w9[2]*ar
                 + w9[3]*bl_ + w9[4]*bm + w9[5]*br
                 + w9[6]*cle + w9[7]*cc + w9[8]*cr;
        };

        float xm2 = ldx(y0 - 2), xm1 = ldx(y0 - 1), x0v = ldx(y0), xp1 = ldx(y0 + 1);
        float vm1 = (y0 - 1 >= 0) ? (bvc + conv3(wv, xm2, xm1, x0v)) : 0.f;
        float v0  = bvc + conv3(wv, xm1, x0v, xp1);

        size_t base = ((size_t)b * NC + c) * NHW;
#pragma unroll
        for (int yi = 0; yi < 8; yi++) {
            int y = y0 + yi;
            float xp2 = ldx(y + 2);
            float vp1 = (y + 1 <= 63) ? (bvc + conv3(wv, x0v, xp1, xp2)) : 0.f;
            float kk  = bkc + conv3(wk, xm1, x0v, xp1);
            float ll  = blc + conv3(wl, vm1, v0, vp1);
            size_t o = base + y * 64 + xx0;
            k_bf[o]     = f2b(kk);
            vN8[o]      = f2f8(v0);
            local_bf[o] = f2b(ll);
            xm1 = x0v; x0v = xp1; xp1 = xp2;
            vm1 = v0;  v0 = vp1;
        }
        return;
    }
    {
        // ---- transpose-convert x ----
        u16 (*tile)[72] = reinterpret_cast<u16 (*)[72]>(pshm);
        int l = bid - 2692;
        int n0 = (l & 63) * 64;
        int c0 = ((l >> 6) & 3) * 64;
        int b  = l >> 8;
        const float* src = x + (size_t)b * NC * NHW;
        u16* dst = xT + (size_t)b * NHW * NC;
        int c = t >> 2, nb = (t & 3) * 16;
#pragma unroll
        for (int q = 0; q < 4; q++) {
            float4 v = *(const float4*)(src + (size_t)(c0 + c) * NHW + n0 + nb + q * 4);
            tile[c][nb + q * 4 + 0] = f2b(v.x);
            tile[c][nb + q * 4 + 1] = f2b(v.y);
            tile[c][nb + q * 4 + 2] = f2b(v.z);
            tile[c][nb + q * 4 + 3] = f2b(v.w);
        }
        __syncthreads();
        int cl = t & 63, ng = t >> 6;
#pragma unroll
        for (int j = 0; j < 16; j++) {
            int n = ng * 16 + j;
            dst[(size_t)(n0 + n) * NC + c0 + cl] = tile[cl][n];
        }
    }
}

// ---------- mid: transpose (k->kT8, local->localT) | gemm_q (qT8 = fp8(xT.Wq^T+bq)) ----------
// blocks [0,2048): transpose; [2048,2560): gemm_q
__global__ __launch_bounds__(256) void mid(
    const u16* __restrict__ k_bf, const u16* __restrict__ local_bf,
    u8* __restrict__ kT8, u16* __restrict__ localT,
    const u16* __restrict__ xT, const u16* __restrict__ Wqb, const float* __restrict__ bq,
    u8* __restrict__ qT8)
{
    __shared__ __align__(16) u16 tile[64][72];
    const int t = threadIdx.x;
    const int bid = blockIdx.x;
    if (bid < 2048) {
        int n0 = (bid & 63) * 64, c0 = ((bid >> 6) & 3) * 64;
        int zb = bid >> 8, b = zb >> 1;
        const u16* src = (zb & 1) ? local_bf : k_bf;
        src += (size_t)b * NC * NHW;
        int c = t >> 2, nb = (t & 3) * 16;
        *(short8s*)&tile[c][nb]     = *(const short8s*)(src + (size_t)(c0 + c) * NHW + n0 + nb);
        *(short8s*)&tile[c][nb + 8] = *(const short8s*)(src + (size_t)(c0 + c) * NHW + n0 + nb + 8);
        __syncthreads();
        int cl = t & 63, ng = t >> 6;
        if (zb & 1) {
            u16* dst = localT + (size_t)b * NHW * NC;
#pragma unroll
            for (int j = 0; j < 16; j++) {
                int n = ng * 16 + j;
                dst[(size_t)(n0 + n) * NC + c0 + cl] = tile[cl][n];
            }
        } else {
            u8* dst = kT8 + (size_t)b * NHW * NC;
#pragma unroll
            for (int j = 0; j < 16; j++) {
                int n = ng * 16 + j;
                dst[(size_t)(n0 + n) * NC + c0 + cl] = f2f8(b2f(tile[cl][n]));
            }
        }
        return;
    }
    {
        const int w = t >> 6, lane = t & 63;
        const int lm = lane & 15, quad = lane >> 4;
        const int l = bid - 2048;
        const int b = l >> 7;
        const int s_base = (l & 127) * 32 + (w & 1) * 16;
        const int ch = (w >> 1) * 128;
        const u16* xTb = xT + (size_t)b * NHW * NC;
        u8* qTb = qT8 + (size_t)b * NHW * NC;
        bf16x8 aq[8];
#pragma unroll
        for (int kt = 0; kt < 8; kt++)
            aq[kt] = *(const bf16x8*)(xTb + (size_t)(s_base + lm) * NC + kt * 32 + quad * 8);
        float4v acc[8];
#pragma unroll
        for (int j = 0; j < 8; j++) acc[j] = (float4v){0.f, 0.f, 0.f, 0.f};
#pragma unroll
        for (int kt = 0; kt < 8; kt++) {
#pragma unroll
            for (int j = 0; j < 8; j++) {
                bf16x8 bw = *(const bf16x8*)(Wqb + (size_t)(ch + j * 16 + lm) * 256 + kt * 32 + quad * 8);
                acc[j] = __builtin_amdgcn_mfma_f32_16x16x32_bf16(aq[kt], bw, acc[j], 0, 0, 0);
            }
        }
#pragma unroll
        for (int j = 0; j < 8; j++) {
            int cout = ch + j * 16 + lm;
            float bb = bq[cout];
#pragma unroll
            for (int r = 0; r < 4; r++) {
                int s = s_base + quad * 4 + r;
                qTb[(size_t)s * NC + cout] = f2f8(acc[j][r] + bb);
            }
        }
    }
}

// ---------- staging: K fp8 tile (2 DMA/wave) + V fp8 tile (2 DMA/wave) ----------
__device__ __forceinline__ void stage_tiles(
    const u8* __restrict__ kb, const u8* __restrict__ vb8, int kv0,
    u8* KlB, u8* VlB, int w, int lane)
{
#pragma unroll
    for (int i = 0; i < 2; i++) {
        int g = (w * 2 + i) * 64 + lane;
        int n = g >> 4, jj = g & 15, cc = jj ^ (n & 15);
        load_lds16(kb + (size_t)(kv0 + n) * NC + cc * 16, KlB + (w * 2 + i) * 1024);
    }
#pragma unroll
    for (int i = 0; i < 2; i++) {
        int g = (w * 2 + i) * 64 + lane;
        int c = g >> 1, h = g & 1, e = (c >> 2) & 1;
        load_lds16(vb8 + (size_t)c * NHW + kv0 + (h ^ e) * 16, VlB + (w * 2 + i) * 1024);
    }
}

// ---------- attn (fp8 QK + fp8 PV, permlane32_swap P exchange) | gemm_hid ----------
// blocks [0,512): attn (combo=blockIdx&15 XCD-local); [512,1024): hid
__global__ __launch_bounds__(256, 2) void attn_hid(
    const u8* __restrict__ qT8, const u8* __restrict__ kT8,
    const u8* __restrict__ vN8, u8* __restrict__ Opart8, float* __restrict__ lpart,
    const u16* __restrict__ localT, const u16* __restrict__ Ws1b, const float* __restrict__ bs1,
    u16* __restrict__ hidT)
{
    __shared__ __align__(16) u8 Kl[2][BC * 256];   // 2 x 8KB fp8
    __shared__ __align__(16) u8 Vl[2][256 * BC];   // 2 x 8KB fp8

    const int t = threadIdx.x;
    const int w = t >> 6, lane = t & 63;

    if (blockIdx.x >= 512) {
        // ---- gemm_hid zone ----
        const int lm = lane & 15, quad = lane >> 4;
        const int l = blockIdx.x - 512;
        const int b = l >> 7;
        const int s_base = (l & 127) * 32 + (w & 1) * 16;
        const int ch = (w >> 1) * 32;
        const u16* lTb = localT + (size_t)b * NHW * NC;
        u16* hTb = hidT + (size_t)b * NHW * 64;
        bf16x8 ah[8];
#pragma unroll
        for (int kt = 0; kt < 8; kt++)
            ah[kt] = *(const bf16x8*)(lTb + (size_t)(s_base + lm) * NC + kt * 32 + quad * 8);
        float4v acc[2];
#pragma unroll
        for (int j = 0; j < 2; j++) acc[j] = (float4v){0.f, 0.f, 0.f, 0.f};
#pragma unroll
        for (int kt = 0; kt < 8; kt++) {
#pragma unroll
            for (int j = 0; j < 2; j++) {
                bf16x8 bw = *(const bf16x8*)(Ws1b + (size_t)(ch + j * 16 + lm) * 256 + kt * 32 + quad * 8);
                acc[j] = __builtin_amdgcn_mfma_f32_16x16x32_bf16(ah[kt], bw, acc[j], 0, 0, 0);
            }
        }
#pragma unroll
        for (int j = 0; j < 2; j++) {
            int h = ch + j * 16 + lm;
            float bb = bs1[h];
#pragma unroll
            for (int r = 0; r < 4; r++) {
                int s = s_base + quad * 4 + r;
                hTb[(size_t)s * 64 + h] = f2b(fmaxf(acc[j][r] + bb, 0.0f));
            }
        }
        return;
    }

    // ---- attention zone ----
    const int combo = blockIdx.x & 15;
    const int b  = combo >> 2;
    const int jc = combo & 3;
    const int n0 = (blockIdx.x >> 4) * 128;
    const int lr = lane & 31, l5 = lane >> 5;

    const u8* qb = qT8 + (size_t)b * NHW * NC;
    const u8* kb = kT8 + (size_t)b * NHW * NC;
    const u8* vb8 = vN8 + (size_t)b * NC * NHW;

    long aq[16];
    {
        int qrow = n0 + w * 32 + lr;
#pragma unroll
        for (int kt = 0; kt < 16; kt++)
            aq[kt] = *(const long*)(qb + (size_t)qrow * NC + kt * 16 + l5 * 8);
    }

    floatx16 oacc[8];
#pragma unroll
    for (int i = 0; i < 8; i++)
#pragma unroll
        for (int j = 0; j < 16; j++) oacc[i][j] = 0.f;
    float lsum = 0.f;

    const int kvbeg = jc * KVCHUNK;
    stage_tiles(kb, vb8, kvbeg, Kl[0], Vl[0], w, lane);

    int buf = 0;
#pragma unroll 1
    for (int it = 0; it < KVCHUNK / BC; it++) {
        const int kv0 = kvbeg + it * BC;
        const int nxt = (it + 1 < KVCHUNK / BC) ? (kv0 + BC) : kvbeg;
        stage_tiles(kb, vb8, nxt, Kl[buf ^ 1], Vl[buf ^ 1], w, lane);
        asm volatile("s_waitcnt vmcnt(4)" ::: "memory");
        __builtin_amdgcn_s_barrier();

        const u8* KlB = Kl[buf];
        const u8* VlB = Vl[buf];

        // S^T[kv][q]: A = K fp8 [m=kv=lr][k=ch], B = Q fp8 regs
        floatx16 sacc;
#pragma unroll
        for (int j = 0; j < 16; j++) sacc[j] = 0.f;
#pragma unroll
        for (int kt = 0; kt < 16; kt++) {
            long ak = *(const long*)&KlB[lr * 256 + ((kt ^ (lr & 15)) * 16) + l5 * 8];
            sacc = __builtin_amdgcn_mfma_f32_32x32x16_fp8_fp8(ak, aq[kt], sacc, 0, 0, 0);
        }
        // exp + per-q row sum + pack 4 fp8 per dword
        unsigned u0 = 0, u1 = 0, u2 = 0, u3 = 0;
        {
            float p[16];
#pragma unroll
            for (int r = 0; r < 16; r++) {
                p[r] = __expf(sacc[r] * 0.0625f);
                lsum += p[r];
            }
            u0 = __builtin_amdgcn_cvt_pk_fp8_f32(p[0], p[1], 0, false);
            u0 = __builtin_amdgcn_cvt_pk_fp8_f32(p[2], p[3], u0, true);
            u1 = __builtin_amdgcn_cvt_pk_fp8_f32(p[4], p[5], 0, false);
            u1 = __builtin_amdgcn_cvt_pk_fp8_f32(p[6], p[7], u1, true);
            u2 = __builtin_amdgcn_cvt_pk_fp8_f32(p[8], p[9], 0, false);
            u2 = __builtin_amdgcn_cvt_pk_fp8_f32(p[10], p[11], u2, true);
            u3 = __builtin_amdgcn_cvt_pk_fp8_f32(p[12], p[13], 0, false);
            u3 = __builtin_amdgcn_cvt_pk_fp8_f32(p[14], p[15], u3, true);
        }
        // half-wave exchange via VALU permlane32_swap (no LDS pipe):
        // after swap(u0,u1): frag1 = kv{l5*8..l5*8+7}; swap(u2,u3): frag2 = kv{16+l5*8..}
        asm volatile("v_permlane32_swap_b32 %0, %1" : "+v"(u0), "+v"(u1));
        asm volatile("v_permlane32_swap_b32 %0, %1" : "+v"(u2), "+v"(u3));
        long A1 = (long)(((unsigned long long)u1 << 32) | u0);
        long A2 = (long)(((unsigned long long)u3 << 32) | u2);

        // PV fp8: O += P @ V. V B-frag b64 with XOR-2 swizzle (2-way = free)
#pragma unroll
        for (int ct = 0; ct < 8; ct++) {
            int c = ct * 32 + lr;
            int e2 = ((c >> 2) & 1) << 1;
            long bv0 = *(const long*)&VlB[c * 32 + (l5 ^ e2) * 8];
            long bv1 = *(const long*)&VlB[c * 32 + ((l5 ^ 2 ^ e2)) * 8];
            oacc[ct] = __builtin_amdgcn_mfma_f32_32x32x16_fp8_fp8(A1, bv0, oacc[ct], 0, 0, 0);
            oacc[ct] = __builtin_amdgcn_mfma_f32_32x32x16_fp8_fp8(A2, bv1, oacc[ct], 0, 0, 0);
        }
        __builtin_amdgcn_s_barrier();
        buf ^= 1;
    }

    // epilogue: unnormalized partial O (fp8) + partial l
    lsum += __shfl_xor(lsum, 32, 64);
    u8* Ob = Opart8 + ((size_t)(b * NKV + jc) * NHW + n0 + w * 32) * NC;
#pragma unroll
    for (int reg = 0; reg < 16; reg++) {
        int row = (reg & 3) + 8 * (reg >> 2) + 4 * l5;
#pragma unroll
        for (int ct = 0; ct < 8; ct++)
            Ob[(size_t)row * NC + ct * 32 + lr] = f2f8(oacc[ct][reg]);
    }
    if (lane < 32)
        lpart[(size_t)(b * NKV + jc) * NHW + n0 + w * 32 + lr] = lsum;
}

// ---------- combine kv-split partials (gT bf16) + fused gap reduce ----------
__global__ __launch_bounds__(256) void attn_combine(
    const u8* __restrict__ Opart8, const float* __restrict__ lpart,
    u16* __restrict__ gT, float* __restrict__ gap)
{
    __shared__ float gsum[256];
    int t = threadIdx.x;
    gsum[t] = 0.f;
    __syncthreads();
    int b = blockIdx.y;
    int n = blockIdx.x * 8 + (t >> 5);
    int c0 = (t & 31) * 8;
    float acc[8] = {};
    float l = 0.f;
#pragma unroll
    for (int j = 0; j < NKV; j++) {
        const u8* op = Opart8 + ((size_t)(b * NKV + j) * NHW + n) * NC + c0;
        unsigned long long v = *(const unsigned long long*)op;
        unsigned lo = (unsigned)v, hi = (unsigned)(v >> 32);
        acc[0] += __builtin_amdgcn_cvt_f32_fp8(lo, 0);
        acc[1] += __builtin_amdgcn_cvt_f32_fp8(lo, 1);
        acc[2] += __builtin_amdgcn_cvt_f32_fp8(lo, 2);
        acc[3] += __builtin_amdgcn_cvt_f32_fp8(lo, 3);
        acc[4] += __builtin_amdgcn_cvt_f32_fp8(hi, 0);
        acc[5] += __builtin_amdgcn_cvt_f32_fp8(hi, 1);
        acc[6] += __builtin_amdgcn_cvt_f32_fp8(hi, 2);
        acc[7] += __builtin_amdgcn_cvt_f32_fp8(hi, 3);
        l += lpart[(size_t)(b * NKV + j) * NHW + n];
    }
    float inv = 1.0f / l;
#pragma unroll
    for (int i = 0; i < 8; i++) acc[i] *= inv;
    short8s vo;
#pragma unroll
    for (int i = 0; i < 8; i++) ((u16*)&vo)[i] = f2b(acc[i]);
    *(short8s*)(gT + ((size_t)b * NHW + n) * NC + c0) = vo;
#pragma unroll
    for (int i = 0; i < 8; i++) atomicAdd(&gsum[c0 + i], acc[i]);
    __syncthreads();
    atomicAdd(&gap[b * NC + t], gsum[t]);
}

// ---------- MFMA GEMM + inline channel-MLP + fuse ----------
__global__ __launch_bounds__(256) void gemm_swfused_mfma(
    const u16* __restrict__ hidT, const u16* __restrict__ Ws2b, const float* __restrict__ bs2,
    const u16* __restrict__ gT, const u16* __restrict__ localT,
    const float* __restrict__ gap,
    const float* __restrict__ Wc1, const float* __restrict__ bc1,
    const float* __restrict__ Wc2, const float* __restrict__ bc2,
    u16* __restrict__ fusedT)
{
    __shared__ float g[256], h1[32], cwl[256];
    __shared__ float ph[32][9];
    const int t = threadIdx.x, w = t >> 6, lane = t & 63;
    const int lm = lane & 15, quad = lane >> 4;
    const int b = blockIdx.y;

    g[t] = gap[b * 256 + t] * (1.0f / 4096.0f);
    __syncthreads();
    {
        int h = t & 31, part = t >> 5;
        float s = 0.f;
        for (int c = part * 32; c < part * 32 + 32; c++) s += Wc1[h * 256 + c] * g[c];
        ph[h][part] = s;
    }
    __syncthreads();
    if (t < 32) {
        float s = bc1[t];
#pragma unroll
        for (int p = 0; p < 8; p++) s += ph[t][p];
        h1[t] = fmaxf(s, 0.f);
    }
    __syncthreads();
    {
        float s = bc2[t];
#pragma unroll
        for (int j = 0; j < 32; j++) s += Wc2[t * 32 + j] * h1[j];
        cwl[t] = 1.0f / (1.0f + __expf(-s));
    }
    __syncthreads();

    const int s_base = blockIdx.x * 32 + (w & 1) * 16;
    const int ch = (w >> 1) * 128;
    const u16* hTb = hidT + (size_t)b * NHW * 64;
    const u16* lTb = localT + (size_t)b * NHW * NC;
    const u16* gTb = gT + (size_t)b * NHW * NC;
    u16* fTb = fusedT + (size_t)b * NHW * NC;

    bf16x8 aq[2];
#pragma unroll
    for (int kt = 0; kt < 2; kt++)
        aq[kt] = *(const bf16x8*)(hTb + (size_t)(s_base + lm) * 64 + kt * 32 + quad * 8);

    float4v acc[8];
#pragma unroll
    for (int j = 0; j < 8; j++) acc[j] = (float4v){0.f, 0.f, 0.f, 0.f};

#pragma unroll
    for (int kt = 0; kt < 2; kt++) {
#pragma unroll
        for (int j = 0; j < 8; j++) {
            bf16x8 bw = *(const bf16x8*)(Ws2b + (size_t)(ch + j * 16 + lm) * 64 + kt * 32 + quad * 8);
            acc[j] = __builtin_amdgcn_mfma_f32_16x16x32_bf16(aq[kt], bw, acc[j], 0, 0, 0);
        }
    }
#pragma unroll
    for (int j = 0; j < 8; j++) {
        int c = ch + j * 16 + lm;
        float bb = bs2[c];
        float cwv = cwl[c];
#pragma unroll
        for (int r = 0; r < 4; r++) {
            int s = s_base + quad * 4 + r;
            float sw = 1.0f / (1.0f + __expf(-(acc[j][r] + bb)));
            float gg = b2f(gTb[(size_t)s * NC + c]);
            float lo = b2f(lTb[(size_t)s * NC + c]);
            fTb[(size_t)s * NC + c] = f2b(gg * cwv + lo * sw);
        }
    }
}

// ---------- MFMA GEMM: out[o][n] = Wo[o][:] . fusedT[n][:] + bo + x ----------
__global__ __launch_bounds__(256) void gemm_out_mfma(
    const u16* __restrict__ Wob, const u16* __restrict__ fusedT, const float* __restrict__ bo,
    const float* __restrict__ x, float* __restrict__ out)
{
    const int t = threadIdx.x, w = t >> 6, lane = t & 63;
    const int lm = lane & 15, quad = lane >> 4;
    const int b = blockIdx.z;
    const int o_base = blockIdx.x * 32 + (w & 1) * 16;
    const int n_base = blockIdx.y * 256 + (w >> 1) * 128;
    const u16* fTb = fusedT + (size_t)b * NHW * NC;

    bf16x8 aw[8];
#pragma unroll
    for (int kt = 0; kt < 8; kt++)
        aw[kt] = *(const bf16x8*)(Wob + (size_t)(o_base + lm) * 256 + kt * 32 + quad * 8);

    float4v acc[8];
#pragma unroll
    for (int j = 0; j < 8; j++) acc[j] = (float4v){0.f, 0.f, 0.f, 0.f};

#pragma unroll
    for (int kt = 0; kt < 8; kt++) {
#pragma unroll
        for (int j = 0; j < 8; j++) {
            bf16x8 bf = *(const bf16x8*)(fTb + (size_t)(n_base + j * 16 + lm) * NC + kt * 32 + quad * 8);
            acc[j] = __builtin_amdgcn_mfma_f32_16x16x32_bf16(aw[kt], bf, acc[j], 0, 0, 0);
        }
    }
#pragma unroll
    for (int r = 0; r < 4; r++) {
        int o = o_base + quad * 4 + r;
        float bb = bo[o];
        size_t rowoff = ((size_t)b * NC + o) * NHW;
#pragma unroll
        for (int j = 0; j < 8; j++) {
            int n = n_base + j * 16 + lm;
            out[rowoff + n] = acc[j][r] + bb + x[rowoff + n];
        }
    }
}

extern "C" void kernel_launch(void* const* d_in, const int* in_sizes, int n_in,
                              void* d_out, int out_size, void* d_ws, size_t ws_size,
                              hipStream_t stream)
{
    const float* x   = (const float*)d_in[0];
    const float* Wq  = (const float*)d_in[1];
    const float* bq  = (const float*)d_in[2];
    const float* Wk  = (const float*)d_in[3];
    const float* bk  = (const float*)d_in[4];
    const float* Wv  = (const float*)d_in[5];
    const float* bv  = (const float*)d_in[6];
    const float* Wl  = (const float*)d_in[7];
    const float* bl  = (const float*)d_in[8];
    const float* Ws1 = (const float*)d_in[9];
    const float* bs1 = (const float*)d_in[10];
    const float* Ws2 = (const float*)d_in[11];
    const float* bs2 = (const float*)d_in[12];
    const float* Wc1 = (const float*)d_in[13];
    const float* bc1 = (const float*)d_in[14];
    const float* Wc2 = (const float*)d_in[15];
    const float* bc2 = (const float*)d_in[16];
    const float* Wo  = (const float*)d_in[17];
    const float* bo  = (const float*)d_in[18];
    float* out = (float*)d_out;

    char* ws = (char*)d_ws;
    u16* k_bf     = (u16*)(ws + OFF_KBF);
    u16* local_bf = (u16*)(ws + OFF_LBF);
    u16* gT       = (u16*)(ws + OFF_GT);
    u16* xT       = (u16*)(ws + OFF_XT);
    u16* fusedT   = (u16*)(ws + OFF_FUSEDT);
    u8*  qT8      = (u8*)(ws + OFF_QT8);
    u8*  kT8      = (u8*)(ws + OFF_KT8);
    u8*  vN8      = (u8*)(ws + OFF_V8);
    u16* localT   = (u16*)(ws + OFF_LT);
    u8*  Opart8   = (u8*)(ws + OFF_OPART);
    float* lpart  = (float*)(ws + OFF_LPART);
    u16* hidT     = (u16*)(ws + OFF_HIDT);
    float* gap    = (float*)(ws + OFF_GAP);
    u16* Wqb      = (u16*)(ws + OFF_WQB);
    u16* Ws1b     = (u16*)(ws + OFF_WS1B);
    u16* Ws2b     = (u16*)(ws + OFF_WS2B);
    u16* Wob      = (u16*)(ws + OFF_WOB);

    prep<<<dim3(3716), 256, 0, stream>>>(x, Wq, Ws1, Ws2, Wo, Wk, bk, Wv, bv, Wl, bl,
                                         Wqb, Ws1b, Ws2b, Wob, gap, k_bf, vN8, local_bf, xT);
    mid<<<dim3(2560), 256, 0, stream>>>(k_bf, local_bf, kT8, localT, xT, Wqb, bq, qT8);
    attn_hid<<<dim3(1024), 256, 0, stream>>>(qT8, kT8, vN8, Opart8, lpart,
                                             localT, Ws1b, bs1, hidT);
    attn_combine<<<dim3(NHW / 8, 4), 256, 0, stream>>>(Opart8, lpart, gT, gap);
    gemm_swfused_mfma<<<dim3(128, 4), 256, 0, stream>>>(hidT, Ws2b, bs2, gT, localT,
                                                        gap, Wc1, bc1, Wc2, bc2, fusedT);
    gemm_out_mfma<<<dim3(8, 16, 4), 256, 0, stream>>>(Wob, fusedT, bo, x, out);
}